// Round 1
// baseline (1337.885 us; speedup 1.0000x reference)
//
#include <hip/hip_runtime.h>
#include <hip/hip_bf16.h>

#define T_TOT 2304
#define S_LEN 128
#define D_IN  1024
#define D_H   64
#define NROW  (2 * T_TOT)
#define CH    (T_TOT / 256)   // 9 elements per thread in row-wide loops
#define SCALE 0.125f          // 1/sqrt(64)

// ---------------------------------------------------------------------------
// Kernel 1: LayerNorm(x_row) @ Wh_seg  -> h[b][t][0:64]
// One block (256 threads) per (b,t) row.
// ---------------------------------------------------------------------------
__global__ __launch_bounds__(256) void k_lnproj(
    const float* __restrict__ x,
    const float* __restrict__ Wh,  const float* __restrict__ Whs, const float* __restrict__ Whe,
    const float* __restrict__ ln_g,  const float* __restrict__ ln_b,
    const float* __restrict__ ln_gs, const float* __restrict__ ln_bs,
    const float* __restrict__ ln_ge, const float* __restrict__ ln_be,
    float* __restrict__ h)
{
    __shared__ float xr[D_IN];
    __shared__ float red[256];

    const int bid = blockIdx.x;
    const int b = bid / T_TOT, t = bid % T_TOT;
    const int tid = threadIdx.x;

    const float* xrow = x + ((size_t)b * T_TOT + t) * D_IN;
    const float *W, *gg, *bb;
    if (t < S_LEN)                { W = Whs; gg = ln_gs; bb = ln_bs; }
    else if (t >= T_TOT - S_LEN)  { W = Whe; gg = ln_ge; bb = ln_be; }
    else                          { W = Wh;  gg = ln_g;  bb = ln_b;  }

    // load row + sum
    float s = 0.f;
    #pragma unroll
    for (int r = 0; r < 4; ++r) {
        float v = xrow[tid + 256 * r];
        xr[tid + 256 * r] = v;
        s += v;
    }
    red[tid] = s; __syncthreads();
    for (int off = 128; off > 0; off >>= 1) {
        if (tid < off) red[tid] += red[tid + off];
        __syncthreads();
    }
    const float mean = red[0] * (1.f / D_IN);
    __syncthreads();

    // variance (two-pass)
    float vs = 0.f;
    #pragma unroll
    for (int r = 0; r < 4; ++r) {
        float d = xr[tid + 256 * r] - mean;
        vs += d * d;
    }
    red[tid] = vs; __syncthreads();
    for (int off = 128; off > 0; off >>= 1) {
        if (tid < off) red[tid] += red[tid + off];
        __syncthreads();
    }
    const float rstd = rsqrtf(red[0] * (1.f / D_IN) + 1e-5f);
    __syncthreads();

    // normalize in place
    #pragma unroll
    for (int r = 0; r < 4; ++r) {
        int i = tid + 256 * r;
        xr[i] = (xr[i] - mean) * rstd * gg[i] + bb[i];
    }
    __syncthreads();

    // projection: 4 groups x 64 outputs
    const int grp = tid >> 6, j = tid & 63;
    float acc = 0.f;
    const int i0 = grp * 256;
    for (int i = i0; i < i0 + 256; ++i) acc += xr[i] * W[i * D_H + j];
    red[tid] = acc; __syncthreads();
    if (tid < 64) {
        float o = red[tid] + red[tid + 64] + red[tid + 128] + red[tid + 192];
        h[((size_t)b * T_TOT + t) * D_H + j] = o;
    }
}

// ---------------------------------------------------------------------------
// Kernel 2: q/k/v projections (64x64 per segment). One block (192 thr)/row.
// k written transposed: kT[b][j][t]  (so logits dot is coalesced over s).
// ---------------------------------------------------------------------------
__global__ __launch_bounds__(192) void k_qkv(
    const float* __restrict__ hin,
    const float* __restrict__ Wk,  const float* __restrict__ Wq,  const float* __restrict__ Wv,
    const float* __restrict__ Wks, const float* __restrict__ Wqs, const float* __restrict__ Wvs,
    const float* __restrict__ Wke, const float* __restrict__ Wqe, const float* __restrict__ Wve,
    float* __restrict__ q, float* __restrict__ kT, float* __restrict__ v)
{
    __shared__ float hr[D_H];
    const int bid = blockIdx.x;
    const int b = bid / T_TOT, t = bid % T_TOT;
    const int tid = threadIdx.x;

    const float* hrow = hin + ((size_t)b * T_TOT + t) * D_H;
    if (tid < D_H) hr[tid] = hrow[tid];
    __syncthreads();

    const int which = tid >> 6, j = tid & 63;
    const float* W;
    if (t < S_LEN)               W = which == 0 ? Wks : (which == 1 ? Wqs : Wvs);
    else if (t >= T_TOT - S_LEN) W = which == 0 ? Wke : (which == 1 ? Wqe : Wve);
    else                         W = which == 0 ? Wk  : (which == 1 ? Wq  : Wv);

    float acc = 0.f;
    #pragma unroll
    for (int d = 0; d < D_H; ++d) acc += hr[d] * W[d * D_H + j];

    if (which == 0)      kT[((size_t)b * D_H + j) * T_TOT + t] = acc;
    else if (which == 1) q[((size_t)b * T_TOT + t) * D_H + j] = acc;
    else                 v[((size_t)b * T_TOT + t) * D_H + j] = acc;
}

// ---------------------------------------------------------------------------
// Kernel 3: attention row kernel. One block (256 threads) per (b,t).
// COPE=true adds the sigmoid suffix-sum positional bias (iteration 0).
// ---------------------------------------------------------------------------
template <bool COPE>
__global__ __launch_bounds__(256) void k_attn(
    const float* __restrict__ q, const float* __restrict__ kT,
    const float* __restrict__ v, const float* __restrict__ cope,
    float* __restrict__ out)
{
    __shared__ float qs[D_H];
    __shared__ float lg[T_TOT];                       // logits, later p
    __shared__ float extra[COPE ? 2 * T_TOT : 2];     // pos | logits_int
    __shared__ float red[256];

    const int bid = blockIdx.x;
    const int b = bid / T_TOT, t = bid % T_TOT;
    const int tid = threadIdx.x;

    if (tid < D_H) qs[tid] = q[((size_t)b * T_TOT + t) * D_H + tid];
    __syncthreads();

    const float* kTb = kT + (size_t)b * D_H * T_TOT;

    // ---- logits ----
    if (COPE) {
        for (int r = 0; r < CH; ++r) {
            int sidx = tid + 256 * r;
            float acc = 0.f;
            #pragma unroll
            for (int d = 0; d < D_H; ++d) acc += qs[d] * kTb[d * T_TOT + sidx];
            lg[sidx] = acc;
        }
    } else {
        for (int r = 0; r < CH; ++r) {
            int sidx = tid + 256 * r;
            if (sidx <= t) {
                float acc = 0.f;
                #pragma unroll
                for (int d = 0; d < D_H; ++d) acc += qs[d] * kTb[d * T_TOT + sidx];
                lg[sidx] = acc;
            }
        }
    }
    __syncthreads();

    if (COPE) {
        float* posb = extra;
        float* lint = extra + T_TOT;

        // sigmoid gates + suffix sum (pos[s] = sum_{s'>=s} sigmoid(logits[s']))
        const int base = tid * CH;
        float gv[CH];
        float lsum = 0.f;
        #pragma unroll
        for (int u = 0; u < CH; ++u) {
            float g = 1.f / (1.f + expf(-lg[base + u]));
            gv[u] = g;
            lsum += g;
        }
        red[tid] = lsum; __syncthreads();
        // Hillis-Steele inclusive scan over the 256 chunk sums
        for (int off = 1; off < 256; off <<= 1) {
            float tv = (tid >= off) ? red[tid - off] : 0.f;
            __syncthreads();
            red[tid] += tv;
            __syncthreads();
        }
        const float total = red[255];
        float run = red[tid] - lsum;   // exclusive prefix of earlier chunks
        #pragma unroll
        for (int u = 0; u < CH; ++u) {
            float p = total - run;     // suffix sum at s = base+u
            p = fminf(p, (float)(T_TOT - 1));
            posb[base + u] = p;
            run += gv[u];
        }
        __syncthreads();

        // logits_int row: q . cope_emb[:, n]
        for (int r = 0; r < CH; ++r) {
            int n = tid + 256 * r;
            float acc = 0.f;
            #pragma unroll
            for (int d = 0; d < D_H; ++d) acc += qs[d] * cope[d * T_TOT + n];
            lint[n] = acc;
        }
        __syncthreads();
    }

    // ---- scores (causal) + max ----
    float scv[CH];
    float mx = -3.4e38f;
    for (int r = 0; r < CH; ++r) {
        int sidx = tid + 256 * r;
        float sc = -3.4e38f;
        if (sidx <= t) {
            sc = lg[sidx] * SCALE;
            if (COPE) {
                float p = extra[sidx];
                float pf = floorf(p);
                int fi = (int)pf;
                int ci = (int)ceilf(p);
                float w = p - pf;
                const float* lint = extra + T_TOT;
                sc += lint[ci] * w + lint[fi] * (1.f - w);
            }
            mx = fmaxf(mx, sc);
        }
        scv[r] = sc;
    }
    __syncthreads();
    red[tid] = mx; __syncthreads();
    for (int off = 128; off > 0; off >>= 1) {
        if (tid < off) red[tid] = fmaxf(red[tid], red[tid + off]);
        __syncthreads();
    }
    mx = red[0];
    __syncthreads();

    // ---- exp + sum ----
    float psum = 0.f;
    for (int r = 0; r < CH; ++r) {
        int sidx = tid + 256 * r;
        float pv = 0.f;
        if (sidx <= t) { pv = expf(scv[r] - mx); psum += pv; }
        lg[sidx] = pv;
    }
    red[tid] = psum; __syncthreads();
    for (int off = 128; off > 0; off >>= 1) {
        if (tid < off) red[tid] += red[tid + off];
        __syncthreads();
    }
    const float inv = 1.f / red[0];
    __syncthreads();

    // ---- PV: out[j] = inv * sum_s p[s] * v[s][j] ----
    const int grp = tid >> 6, j = tid & 63;
    float acc = 0.f;
    const float* vb = v + (size_t)b * T_TOT * D_H;
    for (int sidx = grp; sidx <= t; sidx += 4)
        acc += lg[sidx] * vb[(size_t)sidx * D_H + j];
    red[tid] = acc; __syncthreads();
    if (tid < 64) {
        float o = (red[tid] + red[tid + 64] + red[tid + 128] + red[tid + 192]) * inv;
        out[((size_t)b * T_TOT + t) * D_H + j] = o;
    }
}

// ---------------------------------------------------------------------------
extern "C" void kernel_launch(void* const* d_in, const int* in_sizes, int n_in,
                              void* d_out, int out_size, void* d_ws, size_t ws_size,
                              hipStream_t stream) {
    const float* x    = (const float*)d_in[0];
    const float* Wh   = (const float*)d_in[1];
    const float* Whs  = (const float*)d_in[2];
    const float* Whe  = (const float*)d_in[3];
    const float* Wk   = (const float*)d_in[4];
    const float* Wq   = (const float*)d_in[5];
    const float* Wv   = (const float*)d_in[6];
    const float* Wks  = (const float*)d_in[7];
    const float* Wqs  = (const float*)d_in[8];
    const float* Wvs  = (const float*)d_in[9];
    const float* Wke  = (const float*)d_in[10];
    const float* Wqe  = (const float*)d_in[11];
    const float* Wve  = (const float*)d_in[12];
    const float* ln_g  = (const float*)d_in[13];
    const float* ln_b  = (const float*)d_in[14];
    const float* ln_gs = (const float*)d_in[15];
    const float* ln_bs = (const float*)d_in[16];
    const float* ln_ge = (const float*)d_in[17];
    const float* ln_be = (const float*)d_in[18];
    const float* cope  = (const float*)d_in[19];

    float* out = (float*)d_out;

    const size_t N = (size_t)2 * T_TOT * D_H;   // 294912
    float* ws   = (float*)d_ws;
    float* h    = ws;
    float* qb   = h + N;
    float* kT   = qb + N;
    float* vb   = kT + N;
    float* mem1 = vb + N;

    k_lnproj<<<NROW, 256, 0, stream>>>(x, Wh, Whs, Whe,
                                       ln_g, ln_b, ln_gs, ln_bs, ln_ge, ln_be, h);

    // iteration 0
    k_qkv<<<NROW, 192, 0, stream>>>(h, Wk, Wq, Wv, Wks, Wqs, Wvs, Wke, Wqe, Wve,
                                    qb, kT, vb);
    k_attn<true><<<NROW, 256, 0, stream>>>(qb, kT, vb, cope, mem1);

    // iteration 1
    k_qkv<<<NROW, 192, 0, stream>>>(mem1, Wk, Wq, Wv, Wks, Wqs, Wvs, Wke, Wqe, Wve,
                                    qb, kT, vb);
    k_attn<false><<<NROW, 256, 0, stream>>>(qb, kT, vb, nullptr, out);
}

// Round 2
// 319.584 us; speedup vs baseline: 4.1863x; 4.1863x over previous
//
#include <hip/hip_runtime.h>

#define T_TOT 2304
#define S_LEN 128
#define D_IN  1024
#define D_H   64
#define BATCH 2
#define NROW  (BATCH * T_TOT)
#define CH    (T_TOT / 256)   // 9
#define SCALE 0.125f

typedef unsigned short u16;
typedef __attribute__((ext_vector_type(8))) short short8;
typedef __attribute__((ext_vector_type(4))) float f32x4;

static __device__ __forceinline__ u16 f2bf(float f) {
    unsigned u = __float_as_uint(f);
    unsigned r = (u + 0x7fffu + ((u >> 16) & 1u)) >> 16;
    return (u16)r;
}
static __device__ __forceinline__ float bf2f(u16 s) {
    return __uint_as_float((unsigned)s << 16);
}

// ---------------------------------------------------------------------------
// Kernel 1: LayerNorm(x_row) @ Wh_seg  -> h[b][t][0:64]   (fp32, one block/row)
// ---------------------------------------------------------------------------
__global__ __launch_bounds__(256) void k_lnproj(
    const float* __restrict__ x,
    const float* __restrict__ Wh,  const float* __restrict__ Whs, const float* __restrict__ Whe,
    const float* __restrict__ ln_g,  const float* __restrict__ ln_b,
    const float* __restrict__ ln_gs, const float* __restrict__ ln_bs,
    const float* __restrict__ ln_ge, const float* __restrict__ ln_be,
    float* __restrict__ h)
{
    __shared__ float xr[D_IN];
    __shared__ float red[256];

    const int bid = blockIdx.x;
    const int b = bid / T_TOT, t = bid % T_TOT;
    const int tid = threadIdx.x;

    const float* xrow = x + ((size_t)b * T_TOT + t) * D_IN;
    const float *W, *gg, *bb;
    if (t < S_LEN)                { W = Whs; gg = ln_gs; bb = ln_bs; }
    else if (t >= T_TOT - S_LEN)  { W = Whe; gg = ln_ge; bb = ln_be; }
    else                          { W = Wh;  gg = ln_g;  bb = ln_b;  }

    float s = 0.f;
    #pragma unroll
    for (int r = 0; r < 4; ++r) {
        float v = xrow[tid + 256 * r];
        xr[tid + 256 * r] = v;
        s += v;
    }
    red[tid] = s; __syncthreads();
    for (int off = 128; off > 0; off >>= 1) {
        if (tid < off) red[tid] += red[tid + off];
        __syncthreads();
    }
    const float mean = red[0] * (1.f / D_IN);
    __syncthreads();

    float vs = 0.f;
    #pragma unroll
    for (int r = 0; r < 4; ++r) {
        float d = xr[tid + 256 * r] - mean;
        vs += d * d;
    }
    red[tid] = vs; __syncthreads();
    for (int off = 128; off > 0; off >>= 1) {
        if (tid < off) red[tid] += red[tid + off];
        __syncthreads();
    }
    const float rstd = rsqrtf(red[0] * (1.f / D_IN) + 1e-5f);
    __syncthreads();

    #pragma unroll
    for (int r = 0; r < 4; ++r) {
        int i = tid + 256 * r;
        xr[i] = (xr[i] - mean) * rstd * gg[i] + bb[i];
    }
    __syncthreads();

    const int grp = tid >> 6, j = tid & 63;
    float acc = 0.f;
    const int i0 = grp * 256;
    for (int i = i0; i < i0 + 256; ++i) acc += xr[i] * W[i * D_H + j];
    red[tid] = acc; __syncthreads();
    if (tid < 64) {
        float o = red[tid] + red[tid + 64] + red[tid + 128] + red[tid + 192];
        h[((size_t)b * T_TOT + t) * D_H + j] = o;
    }
}

// ---------------------------------------------------------------------------
// Kernel 2: q/k/v projections. SPLIT: write q,k as bf16 hi/lo; v transposed bf16.
// ---------------------------------------------------------------------------
template <bool SPLIT>
__global__ __launch_bounds__(192) void k_qkv(
    const float* __restrict__ hin,
    const float* __restrict__ Wk,  const float* __restrict__ Wq,  const float* __restrict__ Wv,
    const float* __restrict__ Wks, const float* __restrict__ Wqs, const float* __restrict__ Wvs,
    const float* __restrict__ Wke, const float* __restrict__ Wqe, const float* __restrict__ Wve,
    u16* __restrict__ q_hi, u16* __restrict__ q_lo,
    u16* __restrict__ k_hi, u16* __restrict__ k_lo,
    u16* __restrict__ vT)
{
    __shared__ float hr[D_H];
    const int bid = blockIdx.x;
    const int b = bid / T_TOT, t = bid % T_TOT;
    const int tid = threadIdx.x;

    const float* hrow = hin + ((size_t)b * T_TOT + t) * D_H;
    if (tid < D_H) hr[tid] = hrow[tid];
    __syncthreads();

    const int which = tid >> 6, j = tid & 63;
    const float* W;
    if (t < S_LEN)               W = which == 0 ? Wks : (which == 1 ? Wqs : Wvs);
    else if (t >= T_TOT - S_LEN) W = which == 0 ? Wke : (which == 1 ? Wqe : Wve);
    else                         W = which == 0 ? Wk  : (which == 1 ? Wq  : Wv);

    float acc = 0.f;
    #pragma unroll
    for (int d = 0; d < D_H; ++d) acc += hr[d] * W[d * D_H + j];

    const size_t idx = ((size_t)b * T_TOT + t) * D_H + j;
    u16 hi = f2bf(acc);
    if (which == 0) {
        k_hi[idx] = hi;
        if (SPLIT) k_lo[idx] = f2bf(acc - bf2f(hi));
    } else if (which == 1) {
        q_hi[idx] = hi;
        if (SPLIT) q_lo[idx] = f2bf(acc - bf2f(hi));
    } else {
        vT[((size_t)b * D_H + j) * T_TOT + t] = hi;
    }
}

// ---------------------------------------------------------------------------
// cope_emb (64 x T) -> copeT hi/lo (T x 64) bf16
// ---------------------------------------------------------------------------
__global__ __launch_bounds__(256) void k_copeT(
    const float* __restrict__ cope, u16* __restrict__ cT_hi, u16* __restrict__ cT_lo)
{
    int idx = blockIdx.x * 256 + threadIdx.x;     // T_TOT*64 total
    int n = idx >> 6, d = idx & 63;
    float f = cope[(size_t)d * T_TOT + n];
    u16 hi = f2bf(f);
    cT_hi[idx] = hi;
    cT_lo[idx] = f2bf(f - bf2f(hi));
}

// ---------------------------------------------------------------------------
// Score GEMM: out[b][t][s] = sum_d A[b][t][d] * B[b? ][s][d]
// A,B row-major bf16 (64 inner). TERMS=3: split-precision (hi*hi+hi*lo+lo*hi).
// Block: 256 thr = 4 waves; block tile 64(t) x 128(s); wave = 16(t) x 128(s).
// ---------------------------------------------------------------------------
template <int TERMS, bool CAUSAL>
__global__ __launch_bounds__(256) void k_score(
    const u16* __restrict__ a_hi, const u16* __restrict__ a_lo,
    const u16* __restrict__ b_hi, const u16* __restrict__ b_lo,
    long b_batch_stride,
    float* __restrict__ out)
{
    const int b  = blockIdx.z;
    const int s0 = blockIdx.x * 128;
    if (CAUSAL && s0 > blockIdx.y * 64 + 63) return;
    const int t0 = blockIdx.y * 64 + (threadIdx.x >> 6) * 16;
    const int lane = threadIdx.x & 63;
    const int l15 = lane & 15, lg4 = lane >> 4;

    const size_t a_off = ((size_t)(b * T_TOT + t0 + l15)) * D_H + 8 * lg4;
    short8 ah0 = *(const short8*)(a_hi + a_off);
    short8 ah1 = *(const short8*)(a_hi + a_off + 32);
    short8 al0 = {}, al1 = {};
    if (TERMS == 3) {
        al0 = *(const short8*)(a_lo + a_off);
        al1 = *(const short8*)(a_lo + a_off + 32);
    }

    const u16* bh = b_hi + (size_t)b * b_batch_stride;
    const u16* bl = b_lo + (size_t)b * b_batch_stride;

    float* orow = out + ((size_t)(b * T_TOT + t0 + 4 * lg4)) * T_TOT + s0 + l15;

    #pragma unroll
    for (int ni = 0; ni < 8; ++ni) {
        const size_t b_off = ((size_t)(s0 + ni * 16 + l15)) * D_H + 8 * lg4;
        short8 bh0 = *(const short8*)(bh + b_off);
        short8 bh1 = *(const short8*)(bh + b_off + 32);
        f32x4 acc = {0.f, 0.f, 0.f, 0.f};
        if (TERMS == 3) {
            short8 bl0 = *(const short8*)(bl + b_off);
            short8 bl1 = *(const short8*)(bl + b_off + 32);
            acc = __builtin_amdgcn_mfma_f32_16x16x32_bf16(al0, bh0, acc, 0, 0, 0);
            acc = __builtin_amdgcn_mfma_f32_16x16x32_bf16(al1, bh1, acc, 0, 0, 0);
            acc = __builtin_amdgcn_mfma_f32_16x16x32_bf16(ah0, bl0, acc, 0, 0, 0);
            acc = __builtin_amdgcn_mfma_f32_16x16x32_bf16(ah1, bl1, acc, 0, 0, 0);
        }
        acc = __builtin_amdgcn_mfma_f32_16x16x32_bf16(ah0, bh0, acc, 0, 0, 0);
        acc = __builtin_amdgcn_mfma_f32_16x16x32_bf16(ah1, bh1, acc, 0, 0, 0);
        #pragma unroll
        for (int r = 0; r < 4; ++r)
            orow[(size_t)r * T_TOT + ni * 16] = acc[r];
    }
}

// ---------------------------------------------------------------------------
// PV GEMM: out[b][t][j] = sum_s p[b][t][s] * v[b][s][j]
// p: bf16 rows embedded in a float buffer (row stride T_TOT floats = 2*T_TOT u16).
// vT: bf16 [B*64][T]. Wave: 16(t) x 16(j); block covers j 0..63 for one strip.
// ---------------------------------------------------------------------------
__global__ __launch_bounds__(256) void k_pv(
    const float* __restrict__ pbuf, const u16* __restrict__ vT,
    float* __restrict__ out)
{
    const int b  = blockIdx.z;
    const int t0 = blockIdx.x * 16;
    const int j0 = (threadIdx.x >> 6) * 16;
    const int lane = threadIdx.x & 63;
    const int l15 = lane & 15, lg4 = lane >> 4;

    const u16* pb = (const u16*)pbuf;
    const size_t prow = ((size_t)(b * T_TOT + t0 + l15)) * (2 * (size_t)T_TOT);
    const u16* vrow = vT + ((size_t)(b * D_H + j0 + l15)) * T_TOT;

    f32x4 acc = {0.f, 0.f, 0.f, 0.f};
    const int kmax = t0 + 15;
    for (int sc = 0; sc <= kmax; sc += 32) {
        const int off = sc + 8 * lg4;
        short8 a  = *(const short8*)(pb + prow + off);
        short8 bf = *(const short8*)(vrow + off);
        acc = __builtin_amdgcn_mfma_f32_16x16x32_bf16(a, bf, acc, 0, 0, 0);
    }
    float* obase = out + ((size_t)(b * T_TOT + t0 + 4 * lg4)) * D_H + j0 + l15;
    #pragma unroll
    for (int r = 0; r < 4; ++r) obase[(size_t)r * D_H] = acc[r];
}

// ---------------------------------------------------------------------------
// Row kernel: CoPE scan + bias + softmax. Writes normalized p (bf16) into pbase.
// ---------------------------------------------------------------------------
template <bool COPE>
__global__ __launch_bounds__(256) void k_erow(
    const float* __restrict__ logits,
    const float* __restrict__ lint,
    float* __restrict__ pbase)
{
    __shared__ float lg[T_TOT];
    __shared__ float red[256];
    __shared__ float extra[COPE ? 2 * T_TOT : 2];

    const int row = blockIdx.x;
    const int t = row % T_TOT;
    const int tid = threadIdx.x;
    const float* lrow = logits + (size_t)row * T_TOT;

    if (COPE) {
        for (int r = 0; r < CH; ++r) { int s = tid + 256 * r; lg[s] = lrow[s]; }
    } else {
        for (int r = 0; r < CH; ++r) { int s = tid + 256 * r; if (s <= t) lg[s] = lrow[s]; }
    }
    __syncthreads();

    if (COPE) {
        const int base = tid * CH;
        float gv[CH];
        float lsum = 0.f;
        #pragma unroll
        for (int u = 0; u < CH; ++u) {
            float g = 1.f / (1.f + expf(-lg[base + u]));
            gv[u] = g;
            lsum += g;
        }
        red[tid] = lsum; __syncthreads();
        for (int off = 1; off < 256; off <<= 1) {
            float tv = (tid >= off) ? red[tid - off] : 0.f;
            __syncthreads();
            red[tid] += tv;
            __syncthreads();
        }
        const float total = red[255];
        float run = red[tid] - lsum;
        #pragma unroll
        for (int u = 0; u < CH; ++u) {
            float p = fminf(total - run, (float)(T_TOT - 1));
            extra[base + u] = p;
            run += gv[u];
        }
        const float* lintrow = lint + (size_t)row * T_TOT;
        for (int r = 0; r < CH; ++r) { int s = tid + 256 * r; extra[T_TOT + s] = lintrow[s]; }
        __syncthreads();
    }

    // scores (causal) + max
    float scv[CH];
    float mx = -3.4e38f;
    for (int r = 0; r < CH; ++r) {
        int sidx = tid + 256 * r;
        float sc = -3.4e38f;
        if (sidx <= t) {
            sc = lg[sidx] * SCALE;
            if (COPE) {
                float p = extra[sidx];
                float pf = floorf(p);
                int fi = (int)pf;
                int ci = (int)ceilf(p);
                float w = p - pf;
                sc += extra[T_TOT + ci] * w + extra[T_TOT + fi] * (1.f - w);
            }
            mx = fmaxf(mx, sc);
        }
        scv[r] = sc;
    }
    __syncthreads();
    red[tid] = mx; __syncthreads();
    for (int off = 128; off > 0; off >>= 1) {
        if (tid < off) red[tid] = fmaxf(red[tid], red[tid + off]);
        __syncthreads();
    }
    mx = red[0];
    __syncthreads();

    float pvv[CH];
    float psum = 0.f;
    for (int r = 0; r < CH; ++r) {
        int sidx = tid + 256 * r;
        float pv = 0.f;
        if (sidx <= t) { pv = expf(scv[r] - mx); psum += pv; }
        pvv[r] = pv;
    }
    red[tid] = psum; __syncthreads();
    for (int off = 128; off > 0; off >>= 1) {
        if (tid < off) red[tid] += red[tid + off];
        __syncthreads();
    }
    const float inv = 1.f / red[0];

    u16* prow = (u16*)(pbase + (size_t)row * T_TOT);
    for (int r = 0; r < CH; ++r) {
        int sidx = tid + 256 * r;
        prow[sidx] = f2bf(pvv[r] * inv);
    }
}

// ---------------------------------------------------------------------------
extern "C" void kernel_launch(void* const* d_in, const int* in_sizes, int n_in,
                              void* d_out, int out_size, void* d_ws, size_t ws_size,
                              hipStream_t stream) {
    const float* x    = (const float*)d_in[0];
    const float* Wh   = (const float*)d_in[1];
    const float* Whs  = (const float*)d_in[2];
    const float* Whe  = (const float*)d_in[3];
    const float* Wk   = (const float*)d_in[4];
    const float* Wq   = (const float*)d_in[5];
    const float* Wv   = (const float*)d_in[6];
    const float* Wks  = (const float*)d_in[7];
    const float* Wqs  = (const float*)d_in[8];
    const float* Wvs  = (const float*)d_in[9];
    const float* Wke  = (const float*)d_in[10];
    const float* Wqe  = (const float*)d_in[11];
    const float* Wve  = (const float*)d_in[12];
    const float* ln_g  = (const float*)d_in[13];
    const float* ln_b  = (const float*)d_in[14];
    const float* ln_gs = (const float*)d_in[15];
    const float* ln_bs = (const float*)d_in[16];
    const float* ln_ge = (const float*)d_in[17];
    const float* ln_be = (const float*)d_in[18];
    const float* cope  = (const float*)d_in[19];

    float* out = (float*)d_out;

    const size_t N = (size_t)NROW * D_H;        // 294912
    char* W = (char*)d_ws;
    float* h    = (float*)W;  W += N * 4;
    u16* q_hi   = (u16*)W;    W += N * 2;
    u16* q_lo   = (u16*)W;    W += N * 2;
    u16* k_hi   = (u16*)W;    W += N * 2;
    u16* k_lo   = (u16*)W;    W += N * 2;
    u16* vT     = (u16*)W;    W += N * 2;
    u16* cT_hi  = (u16*)W;    W += (size_t)T_TOT * D_H * 2;
    u16* cT_lo  = (u16*)W;    W += (size_t)T_TOT * D_H * 2;
    float* logits = (float*)W; W += (size_t)BATCH * T_TOT * T_TOT * 4;
    float* lint   = (float*)W; W += (size_t)BATCH * T_TOT * T_TOT * 4;   // also holds p (bf16 rows)
    float* mem1   = (float*)W;

    const dim3 sg(T_TOT / 128, T_TOT / 64, BATCH);   // 18 x 36 x 2
    const long kstride = (long)T_TOT * D_H;

    k_lnproj<<<NROW, 256, 0, stream>>>(x, Wh, Whs, Whe,
                                       ln_g, ln_b, ln_gs, ln_bs, ln_ge, ln_be, h);
    k_copeT<<<(T_TOT * D_H) / 256, 256, 0, stream>>>(cope, cT_hi, cT_lo);

    // iteration 0
    k_qkv<true><<<NROW, 192, 0, stream>>>(h, Wk, Wq, Wv, Wks, Wqs, Wvs, Wke, Wqe, Wve,
                                          q_hi, q_lo, k_hi, k_lo, vT);
    k_score<3, false><<<sg, 256, 0, stream>>>(q_hi, q_lo, k_hi, k_lo, kstride, logits);
    k_score<3, false><<<sg, 256, 0, stream>>>(q_hi, q_lo, cT_hi, cT_lo, 0, lint);
    k_erow<true><<<NROW, 256, 0, stream>>>(logits, lint, lint);
    k_pv<<<dim3(T_TOT / 16, 1, BATCH), 256, 0, stream>>>(lint, vT, mem1);

    // iteration 1
    k_qkv<false><<<NROW, 192, 0, stream>>>(mem1, Wk, Wq, Wv, Wks, Wqs, Wvs, Wke, Wqe, Wve,
                                           q_hi, q_lo, k_hi, k_lo, vT);
    k_score<1, true><<<sg, 256, 0, stream>>>(q_hi, q_lo, k_hi, k_lo, kstride, logits);
    k_erow<false><<<NROW, 256, 0, stream>>>(logits, nullptr, lint);
    k_pv<<<dim3(T_TOT / 16, 1, BATCH), 256, 0, stream>>>(lint, vT, out);
}

// Round 3
// 244.033 us; speedup vs baseline: 5.4824x; 1.3096x over previous
//
#include <hip/hip_runtime.h>

#define T_TOT 2304
#define S_LEN 128
#define D_IN  1024
#define D_H   64
#define BATCH 2
#define NROW  (BATCH * T_TOT)
#define CH    (T_TOT / 256)   // 9
#define SCALE 0.125f

typedef unsigned short u16;
typedef __attribute__((ext_vector_type(8))) short short8;
typedef __attribute__((ext_vector_type(4))) float f32x4;
typedef __attribute__((ext_vector_type(4))) unsigned short u16x4;

static __device__ __forceinline__ u16 f2bf(float f) {
    unsigned u = __float_as_uint(f);
    unsigned r = (u + 0x7fffu + ((u >> 16) & 1u)) >> 16;
    return (u16)r;
}
static __device__ __forceinline__ float bf2f(u16 s) {
    return __uint_as_float((unsigned)s << 16);
}

// ---------------------------------------------------------------------------
// Kernel 1a: LayerNorm(x_row) -> xn hi/lo (split bf16). One block (256)/row.
// ---------------------------------------------------------------------------
__global__ __launch_bounds__(256) void k_ln(
    const float* __restrict__ x,
    const float* __restrict__ ln_g,  const float* __restrict__ ln_b,
    const float* __restrict__ ln_gs, const float* __restrict__ ln_bs,
    const float* __restrict__ ln_ge, const float* __restrict__ ln_be,
    u16* __restrict__ xn_hi, u16* __restrict__ xn_lo)
{
    __shared__ float red1[256], red2[256];
    const int row = blockIdx.x;
    const int t = row % T_TOT;
    const int tid = threadIdx.x;

    const float *gg, *bb;
    if (t < S_LEN)               { gg = ln_gs; bb = ln_bs; }
    else if (t >= T_TOT - S_LEN) { gg = ln_ge; bb = ln_be; }
    else                         { gg = ln_g;  bb = ln_b;  }

    const float4 xv = *(const float4*)(x + (size_t)row * D_IN + 4 * tid);
    float s  = xv.x + xv.y + xv.z + xv.w;
    float s2 = xv.x * xv.x + xv.y * xv.y + xv.z * xv.z + xv.w * xv.w;
    red1[tid] = s; red2[tid] = s2; __syncthreads();
    for (int off = 128; off > 0; off >>= 1) {
        if (tid < off) { red1[tid] += red1[tid + off]; red2[tid] += red2[tid + off]; }
        __syncthreads();
    }
    const float mean = red1[0] * (1.f / D_IN);
    const float var  = red2[0] * (1.f / D_IN) - mean * mean;
    const float rstd = rsqrtf(var + 1e-5f);

    const float4 gv = *(const float4*)(gg + 4 * tid);
    const float4 bv = *(const float4*)(bb + 4 * tid);
    float o0 = (xv.x - mean) * rstd * gv.x + bv.x;
    float o1 = (xv.y - mean) * rstd * gv.y + bv.y;
    float o2 = (xv.z - mean) * rstd * gv.z + bv.z;
    float o3 = (xv.w - mean) * rstd * gv.w + bv.w;

    u16x4 hv, lv;
    hv[0] = f2bf(o0); lv[0] = f2bf(o0 - bf2f(hv[0]));
    hv[1] = f2bf(o1); lv[1] = f2bf(o1 - bf2f(hv[1]));
    hv[2] = f2bf(o2); lv[2] = f2bf(o2 - bf2f(hv[2]));
    hv[3] = f2bf(o3); lv[3] = f2bf(o3 - bf2f(hv[3]));
    *(u16x4*)(xn_hi + (size_t)row * D_IN + 4 * tid) = hv;
    *(u16x4*)(xn_lo + (size_t)row * D_IN + 4 * tid) = lv;
}

// ---------------------------------------------------------------------------
// Kernel 1b: transpose+split Wh/Whs/Whe -> WT[seg][64][1024] hi/lo bf16
// ---------------------------------------------------------------------------
__global__ __launch_bounds__(256) void k_wprep(
    const float* __restrict__ Wh, const float* __restrict__ Whs, const float* __restrict__ Whe,
    u16* __restrict__ wT_hi, u16* __restrict__ wT_lo)
{
    const int gid = blockIdx.x * 256 + threadIdx.x;   // 0 .. 3*65536
    const int seg = gid >> 16;
    const int o = gid & 65535;
    const int j = o >> 10, k = o & 1023;
    const float* W = seg == 0 ? Wh : (seg == 1 ? Whs : Whe);
    const float f = W[k * D_H + j];
    const u16 hi = f2bf(f);
    wT_hi[gid] = hi;
    wT_lo[gid] = f2bf(f - bf2f(hi));
}

// ---------------------------------------------------------------------------
// Kernel 1c: h = LN(x) @ W_seg via MFMA, 3-term split. Block = 64 rows x 64 cols.
// ---------------------------------------------------------------------------
__global__ __launch_bounds__(256) void k_hgemm(
    const u16* __restrict__ xn_hi, const u16* __restrict__ xn_lo,
    const u16* __restrict__ wT_hi, const u16* __restrict__ wT_lo,
    float* __restrict__ h)
{
    const int tile = blockIdx.x;              // 0..71 ; row0 = tile*64
    const int tt = tile % 36;
    const int seg = tt < 2 ? 1 : (tt >= 34 ? 2 : 0);
    const u16* bh = wT_hi + (size_t)seg * D_H * D_IN;
    const u16* bl = wT_lo + (size_t)seg * D_H * D_IN;

    const int w = threadIdx.x >> 6;
    const int lane = threadIdx.x & 63;
    const int l15 = lane & 15, lg4 = lane >> 4;
    const int row0 = tile * 64 + w * 16;

    const size_t abase = (size_t)(row0 + l15) * D_IN + 8 * lg4;
    f32x4 acc[4] = {};

    for (int kk = 0; kk < D_IN / 32; ++kk) {
        const size_t ao = abase + kk * 32;
        short8 ah = *(const short8*)(xn_hi + ao);
        short8 al = *(const short8*)(xn_lo + ao);
        #pragma unroll
        for (int j = 0; j < 4; ++j) {
            const size_t bo = (size_t)(j * 16 + l15) * D_IN + kk * 32 + 8 * lg4;
            short8 bhf = *(const short8*)(bh + bo);
            short8 blf = *(const short8*)(bl + bo);
            acc[j] = __builtin_amdgcn_mfma_f32_16x16x32_bf16(al, bhf, acc[j], 0, 0, 0);
            acc[j] = __builtin_amdgcn_mfma_f32_16x16x32_bf16(ah, blf, acc[j], 0, 0, 0);
            acc[j] = __builtin_amdgcn_mfma_f32_16x16x32_bf16(ah, bhf, acc[j], 0, 0, 0);
        }
    }
    #pragma unroll
    for (int j = 0; j < 4; ++j)
        #pragma unroll
        for (int r = 0; r < 4; ++r)
            h[(size_t)(row0 + 4 * lg4 + r) * D_H + j * 16 + l15] = acc[j][r];
}

// ---------------------------------------------------------------------------
// Kernel 2: q/k/v projections. SPLIT: write q,k as bf16 hi/lo; v transposed bf16.
// ---------------------------------------------------------------------------
template <bool SPLIT>
__global__ __launch_bounds__(192) void k_qkv(
    const float* __restrict__ hin,
    const float* __restrict__ Wk,  const float* __restrict__ Wq,  const float* __restrict__ Wv,
    const float* __restrict__ Wks, const float* __restrict__ Wqs, const float* __restrict__ Wvs,
    const float* __restrict__ Wke, const float* __restrict__ Wqe, const float* __restrict__ Wve,
    u16* __restrict__ q_hi, u16* __restrict__ q_lo,
    u16* __restrict__ k_hi, u16* __restrict__ k_lo,
    u16* __restrict__ vT)
{
    __shared__ float hr[D_H];
    const int bid = blockIdx.x;
    const int b = bid / T_TOT, t = bid % T_TOT;
    const int tid = threadIdx.x;

    const float* hrow = hin + ((size_t)b * T_TOT + t) * D_H;
    if (tid < D_H) hr[tid] = hrow[tid];
    __syncthreads();

    const int which = tid >> 6, j = tid & 63;
    const float* W;
    if (t < S_LEN)               W = which == 0 ? Wks : (which == 1 ? Wqs : Wvs);
    else if (t >= T_TOT - S_LEN) W = which == 0 ? Wke : (which == 1 ? Wqe : Wve);
    else                         W = which == 0 ? Wk  : (which == 1 ? Wq  : Wv);

    float acc = 0.f;
    #pragma unroll
    for (int d = 0; d < D_H; ++d) acc += hr[d] * W[d * D_H + j];

    const size_t idx = ((size_t)b * T_TOT + t) * D_H + j;
    u16 hi = f2bf(acc);
    if (which == 0) {
        k_hi[idx] = hi;
        if (SPLIT) k_lo[idx] = f2bf(acc - bf2f(hi));
    } else if (which == 1) {
        q_hi[idx] = hi;
        if (SPLIT) q_lo[idx] = f2bf(acc - bf2f(hi));
    } else {
        vT[((size_t)b * D_H + j) * T_TOT + t] = hi;
    }
}

// ---------------------------------------------------------------------------
// cope_emb (64 x T) -> copeT hi/lo (T x 64) bf16
// ---------------------------------------------------------------------------
__global__ __launch_bounds__(256) void k_copeT(
    const float* __restrict__ cope, u16* __restrict__ cT_hi, u16* __restrict__ cT_lo)
{
    int idx = blockIdx.x * 256 + threadIdx.x;     // T_TOT*64 total
    int n = idx >> 6, d = idx & 63;
    float f = cope[(size_t)d * T_TOT + n];
    u16 hi = f2bf(f);
    cT_hi[idx] = hi;
    cT_lo[idx] = f2bf(f - bf2f(hi));
}

// ---------------------------------------------------------------------------
// Score GEMM: out[b][t][s] = sum_d A[b][t][d] * B[b?][s][d]
// ---------------------------------------------------------------------------
template <int TERMS, bool CAUSAL>
__global__ __launch_bounds__(256) void k_score(
    const u16* __restrict__ a_hi, const u16* __restrict__ a_lo,
    const u16* __restrict__ b_hi, const u16* __restrict__ b_lo,
    long b_batch_stride,
    float* __restrict__ out)
{
    const int b  = blockIdx.z;
    const int s0 = blockIdx.x * 128;
    if (CAUSAL && s0 > blockIdx.y * 64 + 63) return;
    const int t0 = blockIdx.y * 64 + (threadIdx.x >> 6) * 16;
    const int lane = threadIdx.x & 63;
    const int l15 = lane & 15, lg4 = lane >> 4;

    const size_t a_off = ((size_t)(b * T_TOT + t0 + l15)) * D_H + 8 * lg4;
    short8 ah0 = *(const short8*)(a_hi + a_off);
    short8 ah1 = *(const short8*)(a_hi + a_off + 32);
    short8 al0 = {}, al1 = {};
    if (TERMS == 3) {
        al0 = *(const short8*)(a_lo + a_off);
        al1 = *(const short8*)(a_lo + a_off + 32);
    }

    const u16* bh = b_hi + (size_t)b * b_batch_stride;
    const u16* bl = b_lo + (size_t)b * b_batch_stride;

    float* orow = out + ((size_t)(b * T_TOT + t0 + 4 * lg4)) * T_TOT + s0 + l15;

    #pragma unroll
    for (int ni = 0; ni < 8; ++ni) {
        const size_t b_off = ((size_t)(s0 + ni * 16 + l15)) * D_H + 8 * lg4;
        short8 bh0 = *(const short8*)(bh + b_off);
        short8 bh1 = *(const short8*)(bh + b_off + 32);
        f32x4 acc = {0.f, 0.f, 0.f, 0.f};
        if (TERMS == 3) {
            short8 bl0 = *(const short8*)(bl + b_off);
            short8 bl1 = *(const short8*)(bl + b_off + 32);
            acc = __builtin_amdgcn_mfma_f32_16x16x32_bf16(al0, bh0, acc, 0, 0, 0);
            acc = __builtin_amdgcn_mfma_f32_16x16x32_bf16(al1, bh1, acc, 0, 0, 0);
            acc = __builtin_amdgcn_mfma_f32_16x16x32_bf16(ah0, bl0, acc, 0, 0, 0);
            acc = __builtin_amdgcn_mfma_f32_16x16x32_bf16(ah1, bl1, acc, 0, 0, 0);
        }
        acc = __builtin_amdgcn_mfma_f32_16x16x32_bf16(ah0, bh0, acc, 0, 0, 0);
        acc = __builtin_amdgcn_mfma_f32_16x16x32_bf16(ah1, bh1, acc, 0, 0, 0);
        #pragma unroll
        for (int r = 0; r < 4; ++r)
            orow[(size_t)r * T_TOT + ni * 16] = acc[r];
    }
}

// ---------------------------------------------------------------------------
// PV GEMM: out[b][t][j] = sum_s p[b][t][s] * v[b][s][j]
// ---------------------------------------------------------------------------
__global__ __launch_bounds__(256) void k_pv(
    const float* __restrict__ pbuf, const u16* __restrict__ vT,
    float* __restrict__ out)
{
    const int b  = blockIdx.z;
    const int t0 = blockIdx.x * 16;
    const int j0 = (threadIdx.x >> 6) * 16;
    const int lane = threadIdx.x & 63;
    const int l15 = lane & 15, lg4 = lane >> 4;

    const u16* pb = (const u16*)pbuf;
    const size_t prow = ((size_t)(b * T_TOT + t0 + l15)) * (2 * (size_t)T_TOT);
    const u16* vrow = vT + ((size_t)(b * D_H + j0 + l15)) * T_TOT;

    f32x4 acc = {0.f, 0.f, 0.f, 0.f};
    const int kmax = t0 + 15;
    for (int sc = 0; sc <= kmax; sc += 32) {
        const int off = sc + 8 * lg4;
        short8 a  = *(const short8*)(pb + prow + off);
        short8 bf = *(const short8*)(vrow + off);
        acc = __builtin_amdgcn_mfma_f32_16x16x32_bf16(a, bf, acc, 0, 0, 0);
    }
    float* obase = out + ((size_t)(b * T_TOT + t0 + 4 * lg4)) * D_H + j0 + l15;
    #pragma unroll
    for (int r = 0; r < 4; ++r) obase[(size_t)r * D_H] = acc[r];
}

// ---------------------------------------------------------------------------
// Row kernel: CoPE scan + bias + softmax. Writes normalized p (bf16) into pbase.
// ---------------------------------------------------------------------------
template <bool COPE>
__global__ __launch_bounds__(256) void k_erow(
    const float* __restrict__ logits,
    const float* __restrict__ lint,
    float* __restrict__ pbase)
{
    __shared__ float lg[T_TOT];
    __shared__ float red[256];
    __shared__ float extra[COPE ? 2 * T_TOT : 2];

    const int row = blockIdx.x;
    const int t = row % T_TOT;
    const int tid = threadIdx.x;
    const float* lrow = logits + (size_t)row * T_TOT;

    if (COPE) {
        for (int r = 0; r < CH; ++r) { int s = tid + 256 * r; lg[s] = lrow[s]; }
    } else {
        for (int r = 0; r < CH; ++r) { int s = tid + 256 * r; if (s <= t) lg[s] = lrow[s]; }
    }
    __syncthreads();

    if (COPE) {
        const int base = tid * CH;
        float gv[CH];
        float lsum = 0.f;
        #pragma unroll
        for (int u = 0; u < CH; ++u) {
            float g = 1.f / (1.f + expf(-lg[base + u]));
            gv[u] = g;
            lsum += g;
        }
        red[tid] = lsum; __syncthreads();
        for (int off = 1; off < 256; off <<= 1) {
            float tv = (tid >= off) ? red[tid - off] : 0.f;
            __syncthreads();
            red[tid] += tv;
            __syncthreads();
        }
        const float total = red[255];
        float run = red[tid] - lsum;
        #pragma unroll
        for (int u = 0; u < CH; ++u) {
            float p = fminf(total - run, (float)(T_TOT - 1));
            extra[base + u] = p;
            run += gv[u];
        }
        const float* lintrow = lint + (size_t)row * T_TOT;
        for (int r = 0; r < CH; ++r) { int s = tid + 256 * r; extra[T_TOT + s] = lintrow[s]; }
        __syncthreads();
    }

    float scv[CH];
    float mx = -3.4e38f;
    for (int r = 0; r < CH; ++r) {
        int sidx = tid + 256 * r;
        float sc = -3.4e38f;
        if (sidx <= t) {
            sc = lg[sidx] * SCALE;
            if (COPE) {
                float p = extra[sidx];
                float pf = floorf(p);
                int fi = (int)pf;
                int ci = (int)ceilf(p);
                float w = p - pf;
                sc += extra[T_TOT + ci] * w + extra[T_TOT + fi] * (1.f - w);
            }
            mx = fmaxf(mx, sc);
        }
        scv[r] = sc;
    }
    __syncthreads();
    red[tid] = mx; __syncthreads();
    for (int off = 128; off > 0; off >>= 1) {
        if (tid < off) red[tid] = fmaxf(red[tid], red[tid + off]);
        __syncthreads();
    }
    mx = red[0];
    __syncthreads();

    float pvv[CH];
    float psum = 0.f;
    for (int r = 0; r < CH; ++r) {
        int sidx = tid + 256 * r;
        float pv = 0.f;
        if (sidx <= t) { pv = expf(scv[r] - mx); psum += pv; }
        pvv[r] = pv;
    }
    red[tid] = psum; __syncthreads();
    for (int off = 128; off > 0; off >>= 1) {
        if (tid < off) red[tid] += red[tid + off];
        __syncthreads();
    }
    const float inv = 1.f / red[0];

    u16* prow = (u16*)(pbase + (size_t)row * T_TOT);
    for (int r = 0; r < CH; ++r) {
        int sidx = tid + 256 * r;
        prow[sidx] = f2bf(pvv[r] * inv);
    }
}

// ---------------------------------------------------------------------------
extern "C" void kernel_launch(void* const* d_in, const int* in_sizes, int n_in,
                              void* d_out, int out_size, void* d_ws, size_t ws_size,
                              hipStream_t stream) {
    const float* x    = (const float*)d_in[0];
    const float* Wh   = (const float*)d_in[1];
    const float* Whs  = (const float*)d_in[2];
    const float* Whe  = (const float*)d_in[3];
    const float* Wk   = (const float*)d_in[4];
    const float* Wq   = (const float*)d_in[5];
    const float* Wv   = (const float*)d_in[6];
    const float* Wks  = (const float*)d_in[7];
    const float* Wqs  = (const float*)d_in[8];
    const float* Wvs  = (const float*)d_in[9];
    const float* Wke  = (const float*)d_in[10];
    const float* Wqe  = (const float*)d_in[11];
    const float* Wve  = (const float*)d_in[12];
    const float* ln_g  = (const float*)d_in[13];
    const float* ln_b  = (const float*)d_in[14];
    const float* ln_gs = (const float*)d_in[15];
    const float* ln_bs = (const float*)d_in[16];
    const float* ln_ge = (const float*)d_in[17];
    const float* ln_be = (const float*)d_in[18];
    const float* cope  = (const float*)d_in[19];

    float* out = (float*)d_out;

    const size_t N = (size_t)NROW * D_H;        // 294912
    char* W = (char*)d_ws;
    u16* xn_hi  = (u16*)W;    W += (size_t)NROW * D_IN * 2;
    u16* xn_lo  = (u16*)W;    W += (size_t)NROW * D_IN * 2;
    u16* wT_hi  = (u16*)W;    W += (size_t)3 * D_H * D_IN * 2;
    u16* wT_lo  = (u16*)W;    W += (size_t)3 * D_H * D_IN * 2;
    float* h    = (float*)W;  W += N * 4;
    u16* q_hi   = (u16*)W;    W += N * 2;
    u16* q_lo   = (u16*)W;    W += N * 2;
    u16* k_hi   = (u16*)W;    W += N * 2;
    u16* k_lo   = (u16*)W;    W += N * 2;
    u16* vT     = (u16*)W;    W += N * 2;
    u16* cT_hi  = (u16*)W;    W += (size_t)T_TOT * D_H * 2;
    u16* cT_lo  = (u16*)W;    W += (size_t)T_TOT * D_H * 2;
    float* logits = (float*)W; W += (size_t)BATCH * T_TOT * T_TOT * 4;
    float* lint   = (float*)W; W += (size_t)BATCH * T_TOT * T_TOT * 4;   // also holds p (bf16 rows)
    float* mem1   = (float*)W;

    const dim3 sg(T_TOT / 128, T_TOT / 64, BATCH);   // 18 x 36 x 2
    const long kstride = (long)T_TOT * D_H;

    k_ln<<<NROW, 256, 0, stream>>>(x, ln_g, ln_b, ln_gs, ln_bs, ln_ge, ln_be,
                                   xn_hi, xn_lo);
    k_wprep<<<768, 256, 0, stream>>>(Wh, Whs, Whe, wT_hi, wT_lo);
    k_copeT<<<(T_TOT * D_H) / 256, 256, 0, stream>>>(cope, cT_hi, cT_lo);
    k_hgemm<<<NROW / 64, 256, 0, stream>>>(xn_hi, xn_lo, wT_hi, wT_lo, h);

    // iteration 0
    k_qkv<true><<<NROW, 192, 0, stream>>>(h, Wk, Wq, Wv, Wks, Wqs, Wvs, Wke, Wqe, Wve,
                                          q_hi, q_lo, k_hi, k_lo, vT);
    k_score<3, false><<<sg, 256, 0, stream>>>(q_hi, q_lo, k_hi, k_lo, kstride, logits);
    k_score<3, false><<<sg, 256, 0, stream>>>(q_hi, q_lo, cT_hi, cT_lo, 0, lint);
    k_erow<true><<<NROW, 256, 0, stream>>>(logits, lint, lint);
    k_pv<<<dim3(T_TOT / 16, 1, BATCH), 256, 0, stream>>>(lint, vT, mem1);

    // iteration 1
    k_qkv<false><<<NROW, 192, 0, stream>>>(mem1, Wk, Wq, Wv, Wks, Wqs, Wvs, Wke, Wqe, Wve,
                                           q_hi, q_lo, k_hi, k_lo, vT);
    k_score<1, true><<<sg, 256, 0, stream>>>(q_hi, q_lo, k_hi, k_lo, kstride, logits);
    k_erow<false><<<NROW, 256, 0, stream>>>(logits, nullptr, lint);
    k_pv<<<dim3(T_TOT / 16, 1, BATCH), 256, 0, stream>>>(lint, vT, out);
}

// Round 4
// 209.776 us; speedup vs baseline: 6.3777x; 1.1633x over previous
//
#include <hip/hip_runtime.h>

#define T_TOT 2304
#define S_LEN 128
#define D_IN  1024
#define D_H   64
#define BATCH 2
#define NROW  (BATCH * T_TOT)
#define CH    (T_TOT / 256)   // 9
#define SCALE 0.125f
#define KCHUNKS 8
#define KCW   (D_IN / KCHUNKS)   // 128

typedef unsigned short u16;
typedef __attribute__((ext_vector_type(8))) short short8;
typedef __attribute__((ext_vector_type(4))) float f32x4;
typedef __attribute__((ext_vector_type(4))) unsigned short u16x4;

static __device__ __forceinline__ u16 f2bf(float f) {
    unsigned u = __float_as_uint(f);
    unsigned r = (u + 0x7fffu + ((u >> 16) & 1u)) >> 16;
    return (u16)r;
}
static __device__ __forceinline__ float bf2f(u16 s) {
    return __uint_as_float((unsigned)s << 16);
}

// ---------------------------------------------------------------------------
// Kernel 1a: LayerNorm(x_row) -> xn hi/lo (split bf16). One block (256)/row.
// ---------------------------------------------------------------------------
__global__ __launch_bounds__(256) void k_ln(
    const float* __restrict__ x,
    const float* __restrict__ ln_g,  const float* __restrict__ ln_b,
    const float* __restrict__ ln_gs, const float* __restrict__ ln_bs,
    const float* __restrict__ ln_ge, const float* __restrict__ ln_be,
    u16* __restrict__ xn_hi, u16* __restrict__ xn_lo)
{
    __shared__ float red1[256], red2[256];
    const int row = blockIdx.x;
    const int t = row % T_TOT;
    const int tid = threadIdx.x;

    const float *gg, *bb;
    if (t < S_LEN)               { gg = ln_gs; bb = ln_bs; }
    else if (t >= T_TOT - S_LEN) { gg = ln_ge; bb = ln_be; }
    else                         { gg = ln_g;  bb = ln_b;  }

    const float4 xv = *(const float4*)(x + (size_t)row * D_IN + 4 * tid);
    float s  = xv.x + xv.y + xv.z + xv.w;
    float s2 = xv.x * xv.x + xv.y * xv.y + xv.z * xv.z + xv.w * xv.w;
    red1[tid] = s; red2[tid] = s2; __syncthreads();
    for (int off = 128; off > 0; off >>= 1) {
        if (tid < off) { red1[tid] += red1[tid + off]; red2[tid] += red2[tid + off]; }
        __syncthreads();
    }
    const float mean = red1[0] * (1.f / D_IN);
    const float var  = red2[0] * (1.f / D_IN) - mean * mean;
    const float rstd = rsqrtf(var + 1e-5f);

    const float4 gv = *(const float4*)(gg + 4 * tid);
    const float4 bv = *(const float4*)(bb + 4 * tid);
    float o0 = (xv.x - mean) * rstd * gv.x + bv.x;
    float o1 = (xv.y - mean) * rstd * gv.y + bv.y;
    float o2 = (xv.z - mean) * rstd * gv.z + bv.z;
    float o3 = (xv.w - mean) * rstd * gv.w + bv.w;

    u16x4 hv, lv;
    hv[0] = f2bf(o0); lv[0] = f2bf(o0 - bf2f(hv[0]));
    hv[1] = f2bf(o1); lv[1] = f2bf(o1 - bf2f(hv[1]));
    hv[2] = f2bf(o2); lv[2] = f2bf(o2 - bf2f(hv[2]));
    hv[3] = f2bf(o3); lv[3] = f2bf(o3 - bf2f(hv[3]));
    *(u16x4*)(xn_hi + (size_t)row * D_IN + 4 * tid) = hv;
    *(u16x4*)(xn_lo + (size_t)row * D_IN + 4 * tid) = lv;
}

// ---------------------------------------------------------------------------
// Kernel 1b: transpose+split Wh/Whs/Whe -> WT[seg][64][1024] hi/lo bf16
// ---------------------------------------------------------------------------
__global__ __launch_bounds__(256) void k_wprep(
    const float* __restrict__ Wh, const float* __restrict__ Whs, const float* __restrict__ Whe,
    u16* __restrict__ wT_hi, u16* __restrict__ wT_lo)
{
    const int gid = blockIdx.x * 256 + threadIdx.x;   // 0 .. 3*65536
    const int seg = gid >> 16;
    const int o = gid & 65535;
    const int j = o >> 10, k = o & 1023;
    const float* W = seg == 0 ? Wh : (seg == 1 ? Whs : Whe);
    const float f = W[k * D_H + j];
    const u16 hi = f2bf(f);
    wT_hi[gid] = hi;
    wT_lo[gid] = f2bf(f - bf2f(hi));
}

// ---------------------------------------------------------------------------
// Kernel 1c: h_part[kc] = LN(x)[:, kc*128:+128] @ W_seg[kc chunk]  (MFMA, split)
// Grid (72, 8). W chunk staged in LDS (XOR-swizzled). 4 waves x 16 rows.
// ---------------------------------------------------------------------------
__global__ __launch_bounds__(256) void k_hgemm(
    const u16* __restrict__ xn_hi, const u16* __restrict__ xn_lo,
    const u16* __restrict__ wT_hi, const u16* __restrict__ wT_lo,
    float* __restrict__ h_part)
{
    const int tile = blockIdx.x;              // 0..71
    const int kc   = blockIdx.y;              // 0..7
    const int k0   = kc * KCW;
    const int tt = tile % 36;
    const int seg = tt < 2 ? 1 : (tt >= 34 ? 2 : 0);

    __shared__ u16 Bh[64 * KCW];
    __shared__ u16 Bl[64 * KCW];

    const int tid = threadIdx.x;
    // stage W chunk: thread -> row r = tid>>2, 32 u16 starting at (tid&3)*32
    {
        const int r = tid >> 2;
        const int c0 = (tid & 3) * 32;
        const u16* sh = wT_hi + ((size_t)seg * D_H + r) * D_IN + k0 + c0;
        const u16* sl = wT_lo + ((size_t)seg * D_H + r) * D_IN + k0 + c0;
        const int sw = (r & 7) << 3;
        #pragma unroll
        for (int u = 0; u < 4; ++u) {
            const int col = c0 + 8 * u;
            *(short8*)&Bh[r * KCW + (col ^ sw)] = *(const short8*)(sh + 8 * u);
            *(short8*)&Bl[r * KCW + (col ^ sw)] = *(const short8*)(sl + 8 * u);
        }
    }
    __syncthreads();

    const int w = tid >> 6;
    const int lane = tid & 63;
    const int l15 = lane & 15, lg4 = lane >> 4;
    const int row0 = tile * 64 + w * 16;

    const size_t abase = (size_t)(row0 + l15) * D_IN + k0 + 8 * lg4;
    f32x4 acc[4] = {};

    #pragma unroll
    for (int kk = 0; kk < KCW / 32; ++kk) {
        short8 ah = *(const short8*)(xn_hi + abase + kk * 32);
        short8 al = *(const short8*)(xn_lo + abase + kk * 32);
        #pragma unroll
        for (int j = 0; j < 4; ++j) {
            const int brow = j * 16 + l15;
            const int col = (kk * 32 + 8 * lg4) ^ ((brow & 7) << 3);
            short8 bh = *(const short8*)&Bh[brow * KCW + col];
            short8 bl = *(const short8*)&Bl[brow * KCW + col];
            acc[j] = __builtin_amdgcn_mfma_f32_16x16x32_bf16(al, bh, acc[j], 0, 0, 0);
            acc[j] = __builtin_amdgcn_mfma_f32_16x16x32_bf16(ah, bl, acc[j], 0, 0, 0);
            acc[j] = __builtin_amdgcn_mfma_f32_16x16x32_bf16(ah, bh, acc[j], 0, 0, 0);
        }
    }
    float* hp = h_part + (size_t)kc * ((size_t)NROW * D_H);
    #pragma unroll
    for (int j = 0; j < 4; ++j)
        #pragma unroll
        for (int r = 0; r < 4; ++r)
            hp[(size_t)(row0 + 4 * lg4 + r) * D_H + j * 16 + l15] = acc[j][r];
}

// ---------------------------------------------------------------------------
// Kernel 1d: h = sum_kc h_part[kc]  (fixed order -> deterministic)
// ---------------------------------------------------------------------------
__global__ __launch_bounds__(256) void k_hred(
    const float* __restrict__ h_part, float* __restrict__ h)
{
    const size_t idx = (size_t)blockIdx.x * 256 + threadIdx.x;
    const size_t N = (size_t)NROW * D_H;
    float s = 0.f;
    #pragma unroll
    for (int kc = 0; kc < KCHUNKS; ++kc) s += h_part[kc * N + idx];
    h[idx] = s;
}

// ---------------------------------------------------------------------------
// Kernel 2: q/k/v projections. SPLIT: write q,k as bf16 hi/lo; v transposed bf16.
// ---------------------------------------------------------------------------
template <bool SPLIT>
__global__ __launch_bounds__(192) void k_qkv(
    const float* __restrict__ hin,
    const float* __restrict__ Wk,  const float* __restrict__ Wq,  const float* __restrict__ Wv,
    const float* __restrict__ Wks, const float* __restrict__ Wqs, const float* __restrict__ Wvs,
    const float* __restrict__ Wke, const float* __restrict__ Wqe, const float* __restrict__ Wve,
    u16* __restrict__ q_hi, u16* __restrict__ q_lo,
    u16* __restrict__ k_hi, u16* __restrict__ k_lo,
    u16* __restrict__ vT)
{
    __shared__ float hr[D_H];
    const int bid = blockIdx.x;
    const int b = bid / T_TOT, t = bid % T_TOT;
    const int tid = threadIdx.x;

    const float* hrow = hin + ((size_t)b * T_TOT + t) * D_H;
    if (tid < D_H) hr[tid] = hrow[tid];
    __syncthreads();

    const int which = tid >> 6, j = tid & 63;
    const float* W;
    if (t < S_LEN)               W = which == 0 ? Wks : (which == 1 ? Wqs : Wvs);
    else if (t >= T_TOT - S_LEN) W = which == 0 ? Wke : (which == 1 ? Wqe : Wve);
    else                         W = which == 0 ? Wk  : (which == 1 ? Wq  : Wv);

    float acc = 0.f;
    #pragma unroll
    for (int d = 0; d < D_H; ++d) acc += hr[d] * W[d * D_H + j];

    const size_t idx = ((size_t)b * T_TOT + t) * D_H + j;
    u16 hi = f2bf(acc);
    if (which == 0) {
        k_hi[idx] = hi;
        if (SPLIT) k_lo[idx] = f2bf(acc - bf2f(hi));
    } else if (which == 1) {
        q_hi[idx] = hi;
        if (SPLIT) q_lo[idx] = f2bf(acc - bf2f(hi));
    } else {
        vT[((size_t)b * D_H + j) * T_TOT + t] = hi;
    }
}

// ---------------------------------------------------------------------------
// cope_emb (64 x T) -> copeT hi/lo (T x 64) bf16
// ---------------------------------------------------------------------------
__global__ __launch_bounds__(256) void k_copeT(
    const float* __restrict__ cope, u16* __restrict__ cT_hi, u16* __restrict__ cT_lo)
{
    int idx = blockIdx.x * 256 + threadIdx.x;     // T_TOT*64 total
    int n = idx >> 6, d = idx & 63;
    float f = cope[(size_t)d * T_TOT + n];
    u16 hi = f2bf(f);
    cT_hi[idx] = hi;
    cT_lo[idx] = f2bf(f - bf2f(hi));
}

// ---------------------------------------------------------------------------
// Score GEMM: out[b][t][s] = sum_d A[b][t][d] * B[b?][s][d]
// ---------------------------------------------------------------------------
template <int TERMS, bool CAUSAL>
__global__ __launch_bounds__(256) void k_score(
    const u16* __restrict__ a_hi, const u16* __restrict__ a_lo,
    const u16* __restrict__ b_hi, const u16* __restrict__ b_lo,
    long b_batch_stride,
    float* __restrict__ out)
{
    const int b  = blockIdx.z;
    const int s0 = blockIdx.x * 128;
    if (CAUSAL && s0 > blockIdx.y * 64 + 63) return;
    const int t0 = blockIdx.y * 64 + (threadIdx.x >> 6) * 16;
    const int lane = threadIdx.x & 63;
    const int l15 = lane & 15, lg4 = lane >> 4;

    const size_t a_off = ((size_t)(b * T_TOT + t0 + l15)) * D_H + 8 * lg4;
    short8 ah0 = *(const short8*)(a_hi + a_off);
    short8 ah1 = *(const short8*)(a_hi + a_off + 32);
    short8 al0 = {}, al1 = {};
    if (TERMS == 3) {
        al0 = *(const short8*)(a_lo + a_off);
        al1 = *(const short8*)(a_lo + a_off + 32);
    }

    const u16* bh = b_hi + (size_t)b * b_batch_stride;
    const u16* bl = b_lo + (size_t)b * b_batch_stride;

    float* orow = out + ((size_t)(b * T_TOT + t0 + 4 * lg4)) * T_TOT + s0 + l15;

    #pragma unroll
    for (int ni = 0; ni < 8; ++ni) {
        const size_t b_off = ((size_t)(s0 + ni * 16 + l15)) * D_H + 8 * lg4;
        short8 bh0 = *(const short8*)(bh + b_off);
        short8 bh1 = *(const short8*)(bh + b_off + 32);
        f32x4 acc = {0.f, 0.f, 0.f, 0.f};
        if (TERMS == 3) {
            short8 bl0 = *(const short8*)(bl + b_off);
            short8 bl1 = *(const short8*)(bl + b_off + 32);
            acc = __builtin_amdgcn_mfma_f32_16x16x32_bf16(al0, bh0, acc, 0, 0, 0);
            acc = __builtin_amdgcn_mfma_f32_16x16x32_bf16(al1, bh1, acc, 0, 0, 0);
            acc = __builtin_amdgcn_mfma_f32_16x16x32_bf16(ah0, bl0, acc, 0, 0, 0);
            acc = __builtin_amdgcn_mfma_f32_16x16x32_bf16(ah1, bl1, acc, 0, 0, 0);
        }
        acc = __builtin_amdgcn_mfma_f32_16x16x32_bf16(ah0, bh0, acc, 0, 0, 0);
        acc = __builtin_amdgcn_mfma_f32_16x16x32_bf16(ah1, bh1, acc, 0, 0, 0);
        #pragma unroll
        for (int r = 0; r < 4; ++r)
            orow[(size_t)r * T_TOT + ni * 16] = acc[r];
    }
}

// ---------------------------------------------------------------------------
// PV GEMM: out[b][t][j] = sum_s p[b][t][s] * v[b][s][j]
// ---------------------------------------------------------------------------
__global__ __launch_bounds__(256) void k_pv(
    const float* __restrict__ pbuf, const u16* __restrict__ vT,
    float* __restrict__ out)
{
    const int b  = blockIdx.z;
    const int t0 = blockIdx.x * 16;
    const int j0 = (threadIdx.x >> 6) * 16;
    const int lane = threadIdx.x & 63;
    const int l15 = lane & 15, lg4 = lane >> 4;

    const u16* pb = (const u16*)pbuf;
    const size_t prow = ((size_t)(b * T_TOT + t0 + l15)) * (2 * (size_t)T_TOT);
    const u16* vrow = vT + ((size_t)(b * D_H + j0 + l15)) * T_TOT;

    f32x4 acc = {0.f, 0.f, 0.f, 0.f};
    const int kmax = t0 + 15;
    for (int sc = 0; sc <= kmax; sc += 32) {
        const int off = sc + 8 * lg4;
        short8 a  = *(const short8*)(pb + prow + off);
        short8 bf = *(const short8*)(vrow + off);
        acc = __builtin_amdgcn_mfma_f32_16x16x32_bf16(a, bf, acc, 0, 0, 0);
    }
    float* obase = out + ((size_t)(b * T_TOT + t0 + 4 * lg4)) * D_H + j0 + l15;
    #pragma unroll
    for (int r = 0; r < 4; ++r) obase[(size_t)r * D_H] = acc[r];
}

// ---------------------------------------------------------------------------
// Row kernel: CoPE scan + bias + softmax. Writes normalized p (bf16) into pbase.
// ---------------------------------------------------------------------------
template <bool COPE>
__global__ __launch_bounds__(256) void k_erow(
    const float* __restrict__ logits,
    const float* __restrict__ lint,
    float* __restrict__ pbase)
{
    __shared__ float lg[T_TOT];
    __shared__ float red[256];
    __shared__ float extra[COPE ? 2 * T_TOT : 2];

    const int row = blockIdx.x;
    const int t = row % T_TOT;
    const int tid = threadIdx.x;
    const float* lrow = logits + (size_t)row * T_TOT;

    if (COPE) {
        for (int r = 0; r < CH; ++r) { int s = tid + 256 * r; lg[s] = lrow[s]; }
    } else {
        for (int r = 0; r < CH; ++r) { int s = tid + 256 * r; if (s <= t) lg[s] = lrow[s]; }
    }
    __syncthreads();

    if (COPE) {
        const int base = tid * CH;
        float gv[CH];
        float lsum = 0.f;
        #pragma unroll
        for (int u = 0; u < CH; ++u) {
            float g = 1.f / (1.f + expf(-lg[base + u]));
            gv[u] = g;
            lsum += g;
        }
        red[tid] = lsum; __syncthreads();
        for (int off = 1; off < 256; off <<= 1) {
            float tv = (tid >= off) ? red[tid - off] : 0.f;
            __syncthreads();
            red[tid] += tv;
            __syncthreads();
        }
        const float total = red[255];
        float run = red[tid] - lsum;
        #pragma unroll
        for (int u = 0; u < CH; ++u) {
            float p = fminf(total - run, (float)(T_TOT - 1));
            extra[base + u] = p;
            run += gv[u];
        }
        const float* lintrow = lint + (size_t)row * T_TOT;
        for (int r = 0; r < CH; ++r) { int s = tid + 256 * r; extra[T_TOT + s] = lintrow[s]; }
        __syncthreads();
    }

    float scv[CH];
    float mx = -3.4e38f;
    for (int r = 0; r < CH; ++r) {
        int sidx = tid + 256 * r;
        float sc = -3.4e38f;
        if (sidx <= t) {
            sc = lg[sidx] * SCALE;
            if (COPE) {
                float p = extra[sidx];
                float pf = floorf(p);
                int fi = (int)pf;
                int ci = (int)ceilf(p);
                float w = p - pf;
                sc += extra[T_TOT + ci] * w + extra[T_TOT + fi] * (1.f - w);
            }
            mx = fmaxf(mx, sc);
        }
        scv[r] = sc;
    }
    __syncthreads();
    red[tid] = mx; __syncthreads();
    for (int off = 128; off > 0; off >>= 1) {
        if (tid < off) red[tid] = fmaxf(red[tid], red[tid + off]);
        __syncthreads();
    }
    mx = red[0];
    __syncthreads();

    float pvv[CH];
    float psum = 0.f;
    for (int r = 0; r < CH; ++r) {
        int sidx = tid + 256 * r;
        float pv = 0.f;
        if (sidx <= t) { pv = expf(scv[r] - mx); psum += pv; }
        pvv[r] = pv;
    }
    red[tid] = psum; __syncthreads();
    for (int off = 128; off > 0; off >>= 1) {
        if (tid < off) red[tid] += red[tid + off];
        __syncthreads();
    }
    const float inv = 1.f / red[0];

    u16* prow = (u16*)(pbase + (size_t)row * T_TOT);
    for (int r = 0; r < CH; ++r) {
        int sidx = tid + 256 * r;
        prow[sidx] = f2bf(pvv[r] * inv);
    }
}

// ---------------------------------------------------------------------------
extern "C" void kernel_launch(void* const* d_in, const int* in_sizes, int n_in,
                              void* d_out, int out_size, void* d_ws, size_t ws_size,
                              hipStream_t stream) {
    const float* x    = (const float*)d_in[0];
    const float* Wh   = (const float*)d_in[1];
    const float* Whs  = (const float*)d_in[2];
    const float* Whe  = (const float*)d_in[3];
    const float* Wk   = (const float*)d_in[4];
    const float* Wq   = (const float*)d_in[5];
    const float* Wv   = (const float*)d_in[6];
    const float* Wks  = (const float*)d_in[7];
    const float* Wqs  = (const float*)d_in[8];
    const float* Wvs  = (const float*)d_in[9];
    const float* Wke  = (const float*)d_in[10];
    const float* Wqe  = (const float*)d_in[11];
    const float* Wve  = (const float*)d_in[12];
    const float* ln_g  = (const float*)d_in[13];
    const float* ln_b  = (const float*)d_in[14];
    const float* ln_gs = (const float*)d_in[15];
    const float* ln_bs = (const float*)d_in[16];
    const float* ln_ge = (const float*)d_in[17];
    const float* ln_be = (const float*)d_in[18];
    const float* cope  = (const float*)d_in[19];

    float* out = (float*)d_out;

    const size_t N = (size_t)NROW * D_H;        // 294912
    char* W = (char*)d_ws;
    u16* xn_hi  = (u16*)W;    W += (size_t)NROW * D_IN * 2;
    u16* xn_lo  = (u16*)W;    W += (size_t)NROW * D_IN * 2;
    u16* wT_hi  = (u16*)W;    W += (size_t)3 * D_H * D_IN * 2;
    u16* wT_lo  = (u16*)W;    W += (size_t)3 * D_H * D_IN * 2;
    float* h    = (float*)W;  W += N * 4;
    u16* q_hi   = (u16*)W;    W += N * 2;
    u16* q_lo   = (u16*)W;    W += N * 2;
    u16* k_hi   = (u16*)W;    W += N * 2;
    u16* k_lo   = (u16*)W;    W += N * 2;
    u16* vT     = (u16*)W;    W += N * 2;
    u16* cT_hi  = (u16*)W;    W += (size_t)T_TOT * D_H * 2;
    u16* cT_lo  = (u16*)W;    W += (size_t)T_TOT * D_H * 2;
    float* logits = (float*)W; W += (size_t)BATCH * T_TOT * T_TOT * 4;
    float* lint   = (float*)W; W += (size_t)BATCH * T_TOT * T_TOT * 4;   // also holds p / h_part
    float* mem1   = (float*)W;

    float* h_part = lint;   // reused before lint is written (8 * N floats)

    const dim3 sg(T_TOT / 128, T_TOT / 64, BATCH);   // 18 x 36 x 2
    const long kstride = (long)T_TOT * D_H;

    k_ln<<<NROW, 256, 0, stream>>>(x, ln_g, ln_b, ln_gs, ln_bs, ln_ge, ln_be,
                                   xn_hi, xn_lo);
    k_wprep<<<768, 256, 0, stream>>>(Wh, Whs, Whe, wT_hi, wT_lo);
    k_copeT<<<(T_TOT * D_H) / 256, 256, 0, stream>>>(cope, cT_hi, cT_lo);
    k_hgemm<<<dim3(NROW / 64, KCHUNKS), 256, 0, stream>>>(xn_hi, xn_lo, wT_hi, wT_lo, h_part);
    k_hred<<<(int)(N / 256), 256, 0, stream>>>(h_part, h);

    // iteration 0
    k_qkv<true><<<NROW, 192, 0, stream>>>(h, Wk, Wq, Wv, Wks, Wqs, Wvs, Wke, Wqe, Wve,
                                          q_hi, q_lo, k_hi, k_lo, vT);
    k_score<3, false><<<sg, 256, 0, stream>>>(q_hi, q_lo, k_hi, k_lo, kstride, logits);
    k_score<3, false><<<sg, 256, 0, stream>>>(q_hi, q_lo, cT_hi, cT_lo, 0, lint);
    k_erow<true><<<NROW, 256, 0, stream>>>(logits, lint, lint);
    k_pv<<<dim3(T_TOT / 16, 1, BATCH), 256, 0, stream>>>(lint, vT, mem1);

    // iteration 1
    k_qkv<false><<<NROW, 192, 0, stream>>>(mem1, Wk, Wq, Wv, Wks, Wqs, Wvs, Wke, Wqe, Wve,
                                           q_hi, q_lo, k_hi, k_lo, vT);
    k_score<1, true><<<sg, 256, 0, stream>>>(q_hi, q_lo, k_hi, k_lo, kstride, logits);
    k_erow<false><<<NROW, 256, 0, stream>>>(logits, nullptr, lint);
    k_pv<<<dim3(T_TOT / 16, 1, BATCH), 256, 0, stream>>>(lint, vT, out);
}

// Round 5
// 189.419 us; speedup vs baseline: 7.0631x; 1.1075x over previous
//
#include <hip/hip_runtime.h>

#define T_TOT 2304
#define S_LEN 128
#define D_IN  1024
#define D_H   64
#define BATCH 2
#define NROW  (BATCH * T_TOT)
#define CH    (T_TOT / 256)   // 9
#define SCALE 0.125f
#define KCHUNKS 8
#define KCW   (D_IN / KCHUNKS)   // 128

typedef unsigned short u16;
typedef __attribute__((ext_vector_type(8))) short short8;
typedef __attribute__((ext_vector_type(4))) float f32x4;
typedef __attribute__((ext_vector_type(4))) unsigned short u16x4;

static __device__ __forceinline__ u16 f2bf(float f) {
    unsigned u = __float_as_uint(f);
    unsigned r = (u + 0x7fffu + ((u >> 16) & 1u)) >> 16;
    return (u16)r;
}
static __device__ __forceinline__ float bf2f(u16 s) {
    return __uint_as_float((unsigned)s << 16);
}

// ---------------------------------------------------------------------------
// Kernel 1a: LayerNorm(x_row) -> xn hi/lo (split bf16). One block (256)/row.
// ---------------------------------------------------------------------------
__global__ __launch_bounds__(256) void k_ln(
    const float* __restrict__ x,
    const float* __restrict__ ln_g,  const float* __restrict__ ln_b,
    const float* __restrict__ ln_gs, const float* __restrict__ ln_bs,
    const float* __restrict__ ln_ge, const float* __restrict__ ln_be,
    u16* __restrict__ xn_hi, u16* __restrict__ xn_lo)
{
    __shared__ float red1[256], red2[256];
    const int row = blockIdx.x;
    const int t = row % T_TOT;
    const int tid = threadIdx.x;

    const float *gg, *bb;
    if (t < S_LEN)               { gg = ln_gs; bb = ln_bs; }
    else if (t >= T_TOT - S_LEN) { gg = ln_ge; bb = ln_be; }
    else                         { gg = ln_g;  bb = ln_b;  }

    const float4 xv = *(const float4*)(x + (size_t)row * D_IN + 4 * tid);
    float s  = xv.x + xv.y + xv.z + xv.w;
    float s2 = xv.x * xv.x + xv.y * xv.y + xv.z * xv.z + xv.w * xv.w;
    red1[tid] = s; red2[tid] = s2; __syncthreads();
    for (int off = 128; off > 0; off >>= 1) {
        if (tid < off) { red1[tid] += red1[tid + off]; red2[tid] += red2[tid + off]; }
        __syncthreads();
    }
    const float mean = red1[0] * (1.f / D_IN);
    const float var  = red2[0] * (1.f / D_IN) - mean * mean;
    const float rstd = rsqrtf(var + 1e-5f);

    const float4 gv = *(const float4*)(gg + 4 * tid);
    const float4 bv = *(const float4*)(bb + 4 * tid);
    float o0 = (xv.x - mean) * rstd * gv.x + bv.x;
    float o1 = (xv.y - mean) * rstd * gv.y + bv.y;
    float o2 = (xv.z - mean) * rstd * gv.z + bv.z;
    float o3 = (xv.w - mean) * rstd * gv.w + bv.w;

    u16x4 hv, lv;
    hv[0] = f2bf(o0); lv[0] = f2bf(o0 - bf2f(hv[0]));
    hv[1] = f2bf(o1); lv[1] = f2bf(o1 - bf2f(hv[1]));
    hv[2] = f2bf(o2); lv[2] = f2bf(o2 - bf2f(hv[2]));
    hv[3] = f2bf(o3); lv[3] = f2bf(o3 - bf2f(hv[3]));
    *(u16x4*)(xn_hi + (size_t)row * D_IN + 4 * tid) = hv;
    *(u16x4*)(xn_lo + (size_t)row * D_IN + 4 * tid) = lv;
}

// ---------------------------------------------------------------------------
// Kernel 1b: prep — transpose+split Wh/Whs/Whe, and split cope_emb^T
// ---------------------------------------------------------------------------
#define WPREP_N (3 * D_H * D_IN)
__global__ __launch_bounds__(256) void k_prep(
    const float* __restrict__ Wh, const float* __restrict__ Whs, const float* __restrict__ Whe,
    const float* __restrict__ cope,
    u16* __restrict__ wT_hi, u16* __restrict__ wT_lo,
    u16* __restrict__ cT_hi, u16* __restrict__ cT_lo)
{
    const int gid = blockIdx.x * 256 + threadIdx.x;
    if (gid < WPREP_N) {
        const int seg = gid >> 16;
        const int o = gid & 65535;
        const int j = o >> 10, k = o & 1023;
        const float* W = seg == 0 ? Wh : (seg == 1 ? Whs : Whe);
        const float f = W[k * D_H + j];
        const u16 hi = f2bf(f);
        wT_hi[gid] = hi;
        wT_lo[gid] = f2bf(f - bf2f(hi));
    } else {
        const int idx = gid - WPREP_N;
        if (idx < T_TOT * D_H) {
            const int n = idx >> 6, d = idx & 63;
            const float f = cope[(size_t)d * T_TOT + n];
            const u16 hi = f2bf(f);
            cT_hi[idx] = hi;
            cT_lo[idx] = f2bf(f - bf2f(hi));
        }
    }
}

// ---------------------------------------------------------------------------
// Kernel 1c: h_part[kc] = LN(x)[:, kc*128:+128] @ W_seg[kc chunk]  (MFMA, split)
// ---------------------------------------------------------------------------
__global__ __launch_bounds__(256) void k_hgemm(
    const u16* __restrict__ xn_hi, const u16* __restrict__ xn_lo,
    const u16* __restrict__ wT_hi, const u16* __restrict__ wT_lo,
    float* __restrict__ h_part)
{
    const int tile = blockIdx.x;              // 0..71
    const int kc   = blockIdx.y;              // 0..7
    const int k0   = kc * KCW;
    const int tt = tile % 36;
    const int seg = tt < 2 ? 1 : (tt >= 34 ? 2 : 0);

    __shared__ u16 Bh[64 * KCW];
    __shared__ u16 Bl[64 * KCW];

    const int tid = threadIdx.x;
    {
        const int r = tid >> 2;
        const int c0 = (tid & 3) * 32;
        const u16* sh = wT_hi + ((size_t)seg * D_H + r) * D_IN + k0 + c0;
        const u16* sl = wT_lo + ((size_t)seg * D_H + r) * D_IN + k0 + c0;
        const int sw = (r & 7) << 3;
        #pragma unroll
        for (int u = 0; u < 4; ++u) {
            const int col = c0 + 8 * u;
            *(short8*)&Bh[r * KCW + (col ^ sw)] = *(const short8*)(sh + 8 * u);
            *(short8*)&Bl[r * KCW + (col ^ sw)] = *(const short8*)(sl + 8 * u);
        }
    }
    __syncthreads();

    const int w = tid >> 6;
    const int lane = tid & 63;
    const int l15 = lane & 15, lg4 = lane >> 4;
    const int row0 = tile * 64 + w * 16;

    const size_t abase = (size_t)(row0 + l15) * D_IN + k0 + 8 * lg4;
    f32x4 acc[4] = {};

    #pragma unroll
    for (int kk = 0; kk < KCW / 32; ++kk) {
        short8 ah = *(const short8*)(xn_hi + abase + kk * 32);
        short8 al = *(const short8*)(xn_lo + abase + kk * 32);
        #pragma unroll
        for (int j = 0; j < 4; ++j) {
            const int brow = j * 16 + l15;
            const int col = (kk * 32 + 8 * lg4) ^ ((brow & 7) << 3);
            short8 bh = *(const short8*)&Bh[brow * KCW + col];
            short8 bl = *(const short8*)&Bl[brow * KCW + col];
            acc[j] = __builtin_amdgcn_mfma_f32_16x16x32_bf16(al, bh, acc[j], 0, 0, 0);
            acc[j] = __builtin_amdgcn_mfma_f32_16x16x32_bf16(ah, bl, acc[j], 0, 0, 0);
            acc[j] = __builtin_amdgcn_mfma_f32_16x16x32_bf16(ah, bh, acc[j], 0, 0, 0);
        }
    }
    float* hp = h_part + (size_t)kc * ((size_t)NROW * D_H);
    #pragma unroll
    for (int j = 0; j < 4; ++j)
        #pragma unroll
        for (int r = 0; r < 4; ++r)
            hp[(size_t)(row0 + 4 * lg4 + r) * D_H + j * 16 + l15] = acc[j][r];
}

// ---------------------------------------------------------------------------
// Kernel 1d: h = sum_kc h_part[kc]
// ---------------------------------------------------------------------------
__global__ __launch_bounds__(256) void k_hred(
    const float* __restrict__ h_part, float* __restrict__ h)
{
    const size_t idx = (size_t)blockIdx.x * 256 + threadIdx.x;
    const size_t N = (size_t)NROW * D_H;
    float s = 0.f;
    #pragma unroll
    for (int kc = 0; kc < KCHUNKS; ++kc) s += h_part[kc * N + idx];
    h[idx] = s;
}

// ---------------------------------------------------------------------------
// Kernel 2: q/k/v projections.
// ---------------------------------------------------------------------------
template <bool SPLIT>
__global__ __launch_bounds__(192) void k_qkv(
    const float* __restrict__ hin,
    const float* __restrict__ Wk,  const float* __restrict__ Wq,  const float* __restrict__ Wv,
    const float* __restrict__ Wks, const float* __restrict__ Wqs, const float* __restrict__ Wvs,
    const float* __restrict__ Wke, const float* __restrict__ Wqe, const float* __restrict__ Wve,
    u16* __restrict__ q_hi, u16* __restrict__ q_lo,
    u16* __restrict__ k_hi, u16* __restrict__ k_lo,
    u16* __restrict__ vT)
{
    __shared__ float hr[D_H];
    const int bid = blockIdx.x;
    const int b = bid / T_TOT, t = bid % T_TOT;
    const int tid = threadIdx.x;

    const float* hrow = hin + ((size_t)b * T_TOT + t) * D_H;
    if (tid < D_H) hr[tid] = hrow[tid];
    __syncthreads();

    const int which = tid >> 6, j = tid & 63;
    const float* W;
    if (t < S_LEN)               W = which == 0 ? Wks : (which == 1 ? Wqs : Wvs);
    else if (t >= T_TOT - S_LEN) W = which == 0 ? Wke : (which == 1 ? Wqe : Wve);
    else                         W = which == 0 ? Wk  : (which == 1 ? Wq  : Wv);

    float acc = 0.f;
    #pragma unroll
    for (int d = 0; d < D_H; ++d) acc += hr[d] * W[d * D_H + j];

    const size_t idx = ((size_t)b * T_TOT + t) * D_H + j;
    u16 hi = f2bf(acc);
    if (which == 0) {
        k_hi[idx] = hi;
        if (SPLIT) k_lo[idx] = f2bf(acc - bf2f(hi));
    } else if (which == 1) {
        q_hi[idx] = hi;
        if (SPLIT) q_lo[idx] = f2bf(acc - bf2f(hi));
    } else {
        vT[((size_t)b * D_H + j) * T_TOT + t] = hi;
    }
}

// ---------------------------------------------------------------------------
// Fused dual score GEMM (iter 0): logits = q.k^T  and  lint = q.cope, both
// 3-term split precision. A fragments loaded once.
// ---------------------------------------------------------------------------
__global__ __launch_bounds__(256) void k_score2(
    const u16* __restrict__ a_hi, const u16* __restrict__ a_lo,
    const u16* __restrict__ k_hi, const u16* __restrict__ k_lo,
    const u16* __restrict__ c_hi, const u16* __restrict__ c_lo,
    float* __restrict__ logits, float* __restrict__ lint)
{
    const int b  = blockIdx.z;
    const int s0 = blockIdx.x * 128;
    const int t0 = blockIdx.y * 64 + (threadIdx.x >> 6) * 16;
    const int lane = threadIdx.x & 63;
    const int l15 = lane & 15, lg4 = lane >> 4;

    const size_t a_off = ((size_t)(b * T_TOT + t0 + l15)) * D_H + 8 * lg4;
    const short8 ah0 = *(const short8*)(a_hi + a_off);
    const short8 ah1 = *(const short8*)(a_hi + a_off + 32);
    const short8 al0 = *(const short8*)(a_lo + a_off);
    const short8 al1 = *(const short8*)(a_lo + a_off + 32);

    const size_t orow_off = ((size_t)(b * T_TOT + t0 + 4 * lg4)) * T_TOT + s0 + l15;

    const u16* bh = k_hi + (size_t)b * (T_TOT * D_H);
    const u16* bl = k_lo + (size_t)b * (T_TOT * D_H);
    float* o = logits + orow_off;
    #pragma unroll
    for (int pass = 0; pass < 2; ++pass) {
        #pragma unroll
        for (int ni = 0; ni < 8; ++ni) {
            const size_t b_off = ((size_t)(s0 + ni * 16 + l15)) * D_H + 8 * lg4;
            short8 bh0 = *(const short8*)(bh + b_off);
            short8 bh1 = *(const short8*)(bh + b_off + 32);
            short8 bl0 = *(const short8*)(bl + b_off);
            short8 bl1 = *(const short8*)(bl + b_off + 32);
            f32x4 acc = {0.f, 0.f, 0.f, 0.f};
            acc = __builtin_amdgcn_mfma_f32_16x16x32_bf16(al0, bh0, acc, 0, 0, 0);
            acc = __builtin_amdgcn_mfma_f32_16x16x32_bf16(al1, bh1, acc, 0, 0, 0);
            acc = __builtin_amdgcn_mfma_f32_16x16x32_bf16(ah0, bl0, acc, 0, 0, 0);
            acc = __builtin_amdgcn_mfma_f32_16x16x32_bf16(ah1, bl1, acc, 0, 0, 0);
            acc = __builtin_amdgcn_mfma_f32_16x16x32_bf16(ah0, bh0, acc, 0, 0, 0);
            acc = __builtin_amdgcn_mfma_f32_16x16x32_bf16(ah1, bh1, acc, 0, 0, 0);
            #pragma unroll
            for (int r = 0; r < 4; ++r)
                o[(size_t)r * T_TOT + ni * 16] = acc[r];
        }
        bh = c_hi; bl = c_lo;      // cope has no batch stride
        o = lint + orow_off;
    }
}

// ---------------------------------------------------------------------------
// Score GEMM (iter 1, causal, 1-term)
// ---------------------------------------------------------------------------
__global__ __launch_bounds__(256) void k_score(
    const u16* __restrict__ a_hi, const u16* __restrict__ b_hi,
    float* __restrict__ out)
{
    const int b  = blockIdx.z;
    const int s0 = blockIdx.x * 128;
    if (s0 > blockIdx.y * 64 + 63) return;
    const int t0 = blockIdx.y * 64 + (threadIdx.x >> 6) * 16;
    const int lane = threadIdx.x & 63;
    const int l15 = lane & 15, lg4 = lane >> 4;

    const size_t a_off = ((size_t)(b * T_TOT + t0 + l15)) * D_H + 8 * lg4;
    short8 ah0 = *(const short8*)(a_hi + a_off);
    short8 ah1 = *(const short8*)(a_hi + a_off + 32);

    const u16* bh = b_hi + (size_t)b * (T_TOT * D_H);
    float* orow = out + ((size_t)(b * T_TOT + t0 + 4 * lg4)) * T_TOT + s0 + l15;

    #pragma unroll
    for (int ni = 0; ni < 8; ++ni) {
        const size_t b_off = ((size_t)(s0 + ni * 16 + l15)) * D_H + 8 * lg4;
        short8 bh0 = *(const short8*)(bh + b_off);
        short8 bh1 = *(const short8*)(bh + b_off + 32);
        f32x4 acc = {0.f, 0.f, 0.f, 0.f};
        acc = __builtin_amdgcn_mfma_f32_16x16x32_bf16(ah0, bh0, acc, 0, 0, 0);
        acc = __builtin_amdgcn_mfma_f32_16x16x32_bf16(ah1, bh1, acc, 0, 0, 0);
        #pragma unroll
        for (int r = 0; r < 4; ++r)
            orow[(size_t)r * T_TOT + ni * 16] = acc[r];
    }
}

// ---------------------------------------------------------------------------
// PV GEMM with 4-way ILP: out[b][t][j] = sum_s p[b][t][s] * v[b][s][j]
// ---------------------------------------------------------------------------
__global__ __launch_bounds__(256) void k_pv(
    const float* __restrict__ pbuf, const u16* __restrict__ vT,
    float* __restrict__ out)
{
    const int b  = blockIdx.z;
    const int t0 = blockIdx.x * 16;
    const int j0 = (threadIdx.x >> 6) * 16;
    const int lane = threadIdx.x & 63;
    const int l15 = lane & 15, lg4 = lane >> 4;

    const u16* pb = (const u16*)pbuf
        + ((size_t)(b * T_TOT + t0 + l15)) * (2 * (size_t)T_TOT) + 8 * lg4;
    const u16* vb = vT + ((size_t)(b * D_H + j0 + l15)) * T_TOT + 8 * lg4;

    f32x4 a0 = {}, a1 = {}, a2 = {}, a3 = {};
    const int smax = t0 + 16;
    int sc = 0;
    for (; sc + 128 <= smax; sc += 128) {
        short8 p0 = *(const short8*)(pb + sc);
        short8 v0 = *(const short8*)(vb + sc);
        short8 p1 = *(const short8*)(pb + sc + 32);
        short8 v1 = *(const short8*)(vb + sc + 32);
        short8 p2 = *(const short8*)(pb + sc + 64);
        short8 v2 = *(const short8*)(vb + sc + 64);
        short8 p3 = *(const short8*)(pb + sc + 96);
        short8 v3 = *(const short8*)(vb + sc + 96);
        a0 = __builtin_amdgcn_mfma_f32_16x16x32_bf16(p0, v0, a0, 0, 0, 0);
        a1 = __builtin_amdgcn_mfma_f32_16x16x32_bf16(p1, v1, a1, 0, 0, 0);
        a2 = __builtin_amdgcn_mfma_f32_16x16x32_bf16(p2, v2, a2, 0, 0, 0);
        a3 = __builtin_amdgcn_mfma_f32_16x16x32_bf16(p3, v3, a3, 0, 0, 0);
    }
    for (; sc < smax; sc += 32) {
        short8 p0 = *(const short8*)(pb + sc);
        short8 v0 = *(const short8*)(vb + sc);
        a0 = __builtin_amdgcn_mfma_f32_16x16x32_bf16(p0, v0, a0, 0, 0, 0);
    }
    f32x4 acc = (a0 + a1) + (a2 + a3);
    float* obase = out + ((size_t)(b * T_TOT + t0 + 4 * lg4)) * D_H + j0 + l15;
    #pragma unroll
    for (int r = 0; r < 4; ++r) obase[(size_t)r * D_H] = acc[r];
}

// ---------------------------------------------------------------------------
// Row kernel: CoPE scan + bias + softmax (shuffle-based reductions).
// ---------------------------------------------------------------------------
template <bool COPE>
__global__ __launch_bounds__(256) void k_erow(
    const float* __restrict__ logits,
    const float* __restrict__ lint,
    float* __restrict__ pbase)
{
    __shared__ float lg[T_TOT];
    __shared__ float extra[COPE ? 2 * T_TOT : 2];
    __shared__ float wtot[4], wmax[4], wsum[4];

    const int row = blockIdx.x;
    const int t = row % T_TOT;
    const int tid = threadIdx.x;
    const int lane = tid & 63, wid = tid >> 6;
    const float* lrow = logits + (size_t)row * T_TOT;

    if (COPE) {
        for (int r = 0; r < CH; ++r) { int s = tid + 256 * r; lg[s] = lrow[s]; }
    } else {
        for (int r = 0; r < CH; ++r) { int s = tid + 256 * r; if (s <= t) lg[s] = lrow[s]; }
    }
    __syncthreads();

    if (COPE) {
        const int base = tid * CH;
        float gv[CH];
        float lsum = 0.f;
        #pragma unroll
        for (int u = 0; u < CH; ++u) {
            float g = 1.f / (1.f + expf(-lg[base + u]));
            gv[u] = g;
            lsum += g;
        }
        // wave-level inclusive scan over per-thread sums
        float cs = lsum;
        #pragma unroll
        for (int off = 1; off < 64; off <<= 1) {
            float n = __shfl_up(cs, off);
            if (lane >= off) cs += n;
        }
        if (lane == 63) wtot[wid] = cs;
        __syncthreads();
        float pre = 0.f, tot = 0.f;
        #pragma unroll
        for (int w = 0; w < 4; ++w) {
            float vv = wtot[w];
            tot += vv;
            if (w < wid) pre += vv;
        }
        float run = pre + cs - lsum;     // exclusive prefix of this thread's chunk
        #pragma unroll
        for (int u = 0; u < CH; ++u) {
            float p = fminf(tot - run, (float)(T_TOT - 1));
            extra[base + u] = p;
            run += gv[u];
        }
        const float* lintrow = lint + (size_t)row * T_TOT;
        for (int r = 0; r < CH; ++r) { int s = tid + 256 * r; extra[T_TOT + s] = lintrow[s]; }
        __syncthreads();
    }

    float scv[CH];
    float mx = -3.4e38f;
    #pragma unroll
    for (int r = 0; r < CH; ++r) {
        int sidx = tid + 256 * r;
        float sc = -3.4e38f;
        if (sidx <= t) {
            sc = lg[sidx] * SCALE;
            if (COPE) {
                float p = extra[sidx];
                float pf = floorf(p);
                int fi = (int)pf;
                int ci = (int)ceilf(p);
                float w = p - pf;
                sc += extra[T_TOT + ci] * w + extra[T_TOT + fi] * (1.f - w);
            }
            mx = fmaxf(mx, sc);
        }
        scv[r] = sc;
    }
    #pragma unroll
    for (int off = 32; off > 0; off >>= 1) mx = fmaxf(mx, __shfl_xor(mx, off));
    if (lane == 0) wmax[wid] = mx;
    __syncthreads();
    mx = fmaxf(fmaxf(wmax[0], wmax[1]), fmaxf(wmax[2], wmax[3]));

    float pvv[CH];
    float psum = 0.f;
    #pragma unroll
    for (int r = 0; r < CH; ++r) {
        int sidx = tid + 256 * r;
        float pv = 0.f;
        if (sidx <= t) { pv = expf(scv[r] - mx); psum += pv; }
        pvv[r] = pv;
    }
    #pragma unroll
    for (int off = 32; off > 0; off >>= 1) psum += __shfl_xor(psum, off);
    if (lane == 0) wsum[wid] = psum;
    __syncthreads();
    const float inv = 1.f / (wsum[0] + wsum[1] + wsum[2] + wsum[3]);

    u16* prow = (u16*)(pbase + (size_t)row * T_TOT);
    #pragma unroll
    for (int r = 0; r < CH; ++r) {
        int sidx = tid + 256 * r;
        prow[sidx] = f2bf(pvv[r] * inv);
    }
}

// ---------------------------------------------------------------------------
extern "C" void kernel_launch(void* const* d_in, const int* in_sizes, int n_in,
                              void* d_out, int out_size, void* d_ws, size_t ws_size,
                              hipStream_t stream) {
    const float* x    = (const float*)d_in[0];
    const float* Wh   = (const float*)d_in[1];
    const float* Whs  = (const float*)d_in[2];
    const float* Whe  = (const float*)d_in[3];
    const float* Wk   = (const float*)d_in[4];
    const float* Wq   = (const float*)d_in[5];
    const float* Wv   = (const float*)d_in[6];
    const float* Wks  = (const float*)d_in[7];
    const float* Wqs  = (const float*)d_in[8];
    const float* Wvs  = (const float*)d_in[9];
    const float* Wke  = (const float*)d_in[10];
    const float* Wqe  = (const float*)d_in[11];
    const float* Wve  = (const float*)d_in[12];
    const float* ln_g  = (const float*)d_in[13];
    const float* ln_b  = (const float*)d_in[14];
    const float* ln_gs = (const float*)d_in[15];
    const float* ln_bs = (const float*)d_in[16];
    const float* ln_ge = (const float*)d_in[17];
    const float* ln_be = (const float*)d_in[18];
    const float* cope  = (const float*)d_in[19];

    float* out = (float*)d_out;

    const size_t N = (size_t)NROW * D_H;        // 294912
    char* W = (char*)d_ws;
    u16* xn_hi  = (u16*)W;    W += (size_t)NROW * D_IN * 2;
    u16* xn_lo  = (u16*)W;    W += (size_t)NROW * D_IN * 2;
    u16* wT_hi  = (u16*)W;    W += (size_t)3 * D_H * D_IN * 2;
    u16* wT_lo  = (u16*)W;    W += (size_t)3 * D_H * D_IN * 2;
    float* h    = (float*)W;  W += N * 4;
    u16* q_hi   = (u16*)W;    W += N * 2;
    u16* q_lo   = (u16*)W;    W += N * 2;
    u16* k_hi   = (u16*)W;    W += N * 2;
    u16* k_lo   = (u16*)W;    W += N * 2;
    u16* vT     = (u16*)W;    W += N * 2;
    u16* cT_hi  = (u16*)W;    W += (size_t)T_TOT * D_H * 2;
    u16* cT_lo  = (u16*)W;    W += (size_t)T_TOT * D_H * 2;
    float* logits = (float*)W; W += (size_t)BATCH * T_TOT * T_TOT * 4;
    float* lint   = (float*)W; W += (size_t)BATCH * T_TOT * T_TOT * 4;   // also holds p / h_part
    float* mem1   = (float*)W;

    float* h_part = lint;   // reused before lint is written (8 * N floats)

    const dim3 sg(T_TOT / 128, T_TOT / 64, BATCH);   // 18 x 36 x 2

    k_ln<<<NROW, 256, 0, stream>>>(x, ln_g, ln_b, ln_gs, ln_bs, ln_ge, ln_be,
                                   xn_hi, xn_lo);
    k_prep<<<(WPREP_N + T_TOT * D_H + 255) / 256, 256, 0, stream>>>(
        Wh, Whs, Whe, cope, wT_hi, wT_lo, cT_hi, cT_lo);
    k_hgemm<<<dim3(NROW / 64, KCHUNKS), 256, 0, stream>>>(xn_hi, xn_lo, wT_hi, wT_lo, h_part);
    k_hred<<<(int)(N / 256), 256, 0, stream>>>(h_part, h);

    // iteration 0
    k_qkv<true><<<NROW, 192, 0, stream>>>(h, Wk, Wq, Wv, Wks, Wqs, Wvs, Wke, Wqe, Wve,
                                          q_hi, q_lo, k_hi, k_lo, vT);
    k_score2<<<sg, 256, 0, stream>>>(q_hi, q_lo, k_hi, k_lo, cT_hi, cT_lo, logits, lint);
    k_erow<true><<<NROW, 256, 0, stream>>>(logits, lint, lint);
    k_pv<<<dim3(T_TOT / 16, 1, BATCH), 256, 0, stream>>>(lint, vT, mem1);

    // iteration 1
    k_qkv<false><<<NROW, 192, 0, stream>>>(mem1, Wk, Wq, Wv, Wks, Wqs, Wvs, Wke, Wqe, Wve,
                                           q_hi, q_lo, k_hi, k_lo, vT);
    k_score<<<sg, 256, 0, stream>>>(q_hi, k_hi, logits);
    k_erow<false><<<NROW, 256, 0, stream>>>(logits, nullptr, lint);
    k_pv<<<dim3(T_TOT / 16, 1, BATCH), 256, 0, stream>>>(lint, vT, out);
}